// Round 9
// baseline (11240.409 us; speedup 1.0000x reference)
//
#include <hip/hip_runtime.h>
#include <math.h>

#define Vz 10000
#define Bz 32
#define Tz 512
#define Hz 512
#define Pz 20
#define POISON 0x7fc00001u

typedef unsigned short u16;
typedef unsigned long long u64;
typedef __attribute__((ext_vector_type(8)))  short bf16x8_t;   // 8 bf16 = 4 VGPR
typedef __attribute__((ext_vector_type(8)))  unsigned short u16x8;
typedef __attribute__((ext_vector_type(16))) float f32x16_t;   // 32x32 acc frag
typedef __attribute__((ext_vector_type(4)))  unsigned u32x4_t;

__device__ __forceinline__ float sigf(float x) { return 1.0f / (1.0f + expf(-x)); }

__device__ __forceinline__ u16 f2bf(float x) {           // round-to-nearest-even
    unsigned u = __float_as_uint(x);
    u += 0x7fff + ((u >> 16) & 1);
    return (u16)(u >> 16);
}
__device__ __forceinline__ float bf2f(u16 h) {
    return __uint_as_float(((unsigned)h) << 16);
}

__device__ __forceinline__ void gload16(const u16* g, const u16* l) {
    __builtin_amdgcn_global_load_lds(
        (const __attribute__((address_space(1))) void*)g,
        (__attribute__((address_space(3))) void*)l, 16, 0, 0);
}

__device__ __forceinline__ u32x4_t make_srsrc(const void* p, unsigned bytes) {
    u32x4_t r;
    r.x = (unsigned)(size_t)p;
    r.y = (unsigned)((size_t)p >> 32);   // stride = 0
    r.z = bytes;                         // num_records (bytes when stride==0)
    r.w = 0x00020000u;                   // raw dword access
    return r;
}

// ---------------------------------------------------------------- splitters
__global__ __launch_bounds__(256) void split_k(const float* __restrict__ src,
                                               u16* __restrict__ dH, u16* __restrict__ dL,
                                               int total4, int srcW4, int dstStride, int colOff) {
    int i = blockIdx.x * 256 + threadIdx.x;
    if (i >= total4) return;
    int row = i / srcW4;
    int c4 = (i - row * srcW4) << 2;
    float4 v = *(const float4*)(src + (size_t)row * ((size_t)srcW4 << 2) + c4);
    ushort4 H, L;
    H.x = f2bf(v.x); L.x = f2bf(v.x - bf2f(H.x));
    H.y = f2bf(v.y); L.y = f2bf(v.y - bf2f(H.y));
    H.z = f2bf(v.z); L.z = f2bf(v.z - bf2f(H.z));
    H.w = f2bf(v.w); L.w = f2bf(v.w - bf2f(H.w));
    size_t d = (size_t)row * dstStride + colOff + c4;
    *(ushort4*)(dH + d) = H;
    *(ushort4*)(dL + d) = L;
}

__global__ __launch_bounds__(256) void embed_split_k(const int* __restrict__ inp,
                                                     const float* __restrict__ etab,
                                                     u16* __restrict__ dH, u16* __restrict__ dL) {
    int i = blockIdx.x * 256 + threadIdx.x;
    int row = i >> 7;
    int c4 = (i & 127) << 2;
    float4 v = *(const float4*)(etab + (size_t)inp[row] * Hz + c4);
    ushort4 H, L;
    H.x = f2bf(v.x); L.x = f2bf(v.x - bf2f(H.x));
    H.y = f2bf(v.y); L.y = f2bf(v.y - bf2f(H.y));
    H.z = f2bf(v.z); L.z = f2bf(v.z - bf2f(H.z));
    H.w = f2bf(v.w); L.w = f2bf(v.w - bf2f(H.w));
    size_t d = (size_t)row * Hz + c4;
    *(ushort4*)(dH + d) = H;
    *(ushort4*)(dL + d) = L;
}

// per-batch transpose + split: enc[b][t][h] -> encT H/L [b][h][t]
__global__ __launch_bounds__(256) void tsplit_k(const float* __restrict__ enc,
                                                u16* __restrict__ dH, u16* __restrict__ dL) {
    __shared__ float ls[64][65];
    const int b = blockIdx.z;
    const int t0 = blockIdx.y * 64;
    const int h0 = blockIdx.x * 64;
    const int tid = threadIdx.x;
    const int rr = tid >> 4;
    const int cc = (tid & 15) << 2;
    const float* eb = enc + (size_t)b * Tz * Hz;
#pragma unroll
    for (int i = 0; i < 4; ++i) {
        int t = rr + i * 16;
        float4 v = *(const float4*)(eb + (size_t)(t0 + t) * Hz + h0 + cc);
        ls[t][cc] = v.x; ls[t][cc + 1] = v.y; ls[t][cc + 2] = v.z; ls[t][cc + 3] = v.w;
    }
    __syncthreads();
    u16* oH = dH + (size_t)b * Tz * Hz;
    u16* oL = dL + (size_t)b * Tz * Hz;
#pragma unroll
    for (int i = 0; i < 4; ++i) {
        int h = rr + i * 16;
        float x0 = ls[cc + 0][h], x1 = ls[cc + 1][h], x2 = ls[cc + 2][h], x3 = ls[cc + 3][h];
        ushort4 H, L;
        H.x = f2bf(x0); L.x = f2bf(x0 - bf2f(H.x));
        H.y = f2bf(x1); L.y = f2bf(x1 - bf2f(H.y));
        H.z = f2bf(x2); L.z = f2bf(x2 - bf2f(H.z));
        H.w = f2bf(x3); L.w = f2bf(x3 - bf2f(H.w));
        size_t d = (size_t)(h0 + h) * Tz + t0 + cc;
        *(ushort4*)(oH + d) = H;
        *(ushort4*)(oL + d) = L;
    }
}

// ------------------------------------------------------------------------------
// bf16x2-split MFMA GEMM (validated rounds 2-8):  C = act(A @ W^T + b1 + b2)
// ------------------------------------------------------------------------------
__device__ __forceinline__ void stage_tiles(const u16 (*L)[128][32],
    const u16* __restrict__ Ah, const u16* __restrict__ Al,
    const u16* __restrict__ Wh, const u16* __restrict__ Wl,
    int m0, int n0, int N, int K, int k0, int w, int l)
{
    const int srow = l >> 2, sslot = l & 3;
#pragma unroll
    for (int h = 0; h < 2; ++h) {
        const int rb = 32 * w + 16 * h;
        const int r = rb + srow;
        const int xr = (r >> 1) & 3;
        const int gk = k0 + ((sslot ^ xr) << 3);
        const size_t ao = (size_t)(m0 + r) * K + gk;
        int nrow = n0 + r; if (nrow >= N) nrow = N - 1;
        const size_t wo = (size_t)nrow * K + gk;
        gload16(Ah + ao, &L[0][rb][0]);
        gload16(Al + ao, &L[1][rb][0]);
        gload16(Wh + wo, &L[2][rb][0]);
        gload16(Wl + wo, &L[3][rb][0]);
    }
}

__global__ __launch_bounds__(256, 2) void gemm_mfma_split(
    const u16* __restrict__ Ah_, const u16* __restrict__ Al_,
    const u16* __restrict__ Wh_, const u16* __restrict__ Wl_,
    const float* __restrict__ b1, const float* __restrict__ b2,
    float* __restrict__ C, u16* __restrict__ CH, u16* __restrict__ CL,
    int M, int N, int K, int omode,
    long bsA, long bsW, int bsCrows, int cstride, int coff)
{
    __shared__ u16 lds[2][4][128][32];
    const int z = blockIdx.z;
    const u16* Ah = Ah_ + (size_t)z * bsA;
    const u16* Al = Al_ + (size_t)z * bsA;
    const u16* Wh = Wh_ + (size_t)z * bsW;
    const u16* Wl = Wl_ + (size_t)z * bsW;
    const int crow0 = z * bsCrows;
    const int tid = threadIdx.x;
    const int w = tid >> 6;
    const int l = tid & 63;
    const int m0 = blockIdx.y * 128;
    const int n0 = blockIdx.x * 128;
    const int wm = (w >> 1) * 64;
    const int wn = (w & 1) * 64;
    const int lr = l & 31;
    const int lk = l >> 5;

    f32x16_t acc[2][2];
#pragma unroll
    for (int si = 0; si < 2; ++si)
#pragma unroll
        for (int ni = 0; ni < 2; ++ni)
#pragma unroll
            for (int q = 0; q < 16; ++q) acc[si][ni][q] = 0.f;

    const int nk = K >> 5;
    stage_tiles(lds[0], Ah, Al, Wh, Wl, m0, n0, N, K, 0, w, l);
    __syncthreads();

    for (int t = 0; t < nk; ++t) {
        const int buf = t & 1;
        if (t + 1 < nk)
            stage_tiles(lds[buf ^ 1], Ah, Al, Wh, Wl, m0, n0, N, K, (t + 1) << 5, w, l);
        const u16 (*L)[128][32] = lds[buf];
#pragma unroll
        for (int kh = 0; kh < 2; ++kh) {
            const int k8 = lk + 2 * kh;
            bf16x8_t aH[2], aL[2], bH[2], bL[2];
#pragma unroll
            for (int si = 0; si < 2; ++si) {
                const int r = wm + si * 32 + lr;
                const int sl = (k8 ^ ((r >> 1) & 3)) << 3;
                aH[si] = *(const bf16x8_t*)&L[0][r][sl];
                aL[si] = *(const bf16x8_t*)&L[1][r][sl];
            }
#pragma unroll
            for (int ni = 0; ni < 2; ++ni) {
                const int r = wn + ni * 32 + lr;
                const int sl = (k8 ^ ((r >> 1) & 3)) << 3;
                bH[ni] = *(const bf16x8_t*)&L[2][r][sl];
                bL[ni] = *(const bf16x8_t*)&L[3][r][sl];
            }
#pragma unroll
            for (int si = 0; si < 2; ++si)
#pragma unroll
                for (int ni = 0; ni < 2; ++ni) {
                    acc[si][ni] = __builtin_amdgcn_mfma_f32_32x32x16_bf16(aH[si], bH[ni], acc[si][ni], 0, 0, 0);
                    acc[si][ni] = __builtin_amdgcn_mfma_f32_32x32x16_bf16(aH[si], bL[ni], acc[si][ni], 0, 0, 0);
                    acc[si][ni] = __builtin_amdgcn_mfma_f32_32x32x16_bf16(aL[si], bH[ni], acc[si][ni], 0, 0, 0);
                }
        }
        __syncthreads();
    }

    const int rbase = 4 * lk;
#pragma unroll
    for (int si = 0; si < 2; ++si)
#pragma unroll
        for (int ni = 0; ni < 2; ++ni) {
            const int n = n0 + wn + ni * 32 + lr;
            if (n >= N) continue;
            const float bias = (b1 ? b1[n] : 0.f) + (b2 ? b2[n] : 0.f);
#pragma unroll
            for (int q = 0; q < 16; ++q) {
                const int m = m0 + wm + si * 32 + (q & 3) + 8 * (q >> 2) + rbase;
                const int crow = crow0 + m;
                float x = acc[si][ni][q] + bias;
                if (omode == 0) {
                    C[(size_t)crow * N + n] = x;
                } else if (omode == 1) {
                    C[(size_t)crow * N + n] = tanhf(x);
                } else {
                    if (omode == 2) x = tanhf(x);
                    u16 h = f2bf(x);
                    CH[(size_t)crow * cstride + coff + n] = h;
                    CL[(size_t)crow * cstride + coff + n] = f2bf(x - bf2f(h));
                }
            }
        }
}

// ------------------------------------------------------------------------------
// Decoder GEMM (validated round 4): A = combH/L pre-split; W = etab fp32,
// split on the fly into swizzled LDS.
// ------------------------------------------------------------------------------
__global__ __launch_bounds__(256, 2) void gemm_dec(
    const u16* __restrict__ Ah, const u16* __restrict__ Al,
    const float* __restrict__ Wf, const float* __restrict__ b1,
    float* __restrict__ C, int M, int N, int K)
{
    __shared__ u16 lA[2][2][128][32];
    __shared__ u16 lB[2][2][128][32];
    const int tid = threadIdx.x;
    const int w = tid >> 6, l = tid & 63;
    const int m0 = blockIdx.y * 128, n0 = blockIdx.x * 128;
    const int wm = (w >> 1) * 64, wn = (w & 1) * 64;
    const int lr = l & 31, lk = l >> 5;
    const int srow = l >> 2, sslot = l & 3;

    f32x16_t acc[2][2];
#pragma unroll
    for (int si = 0; si < 2; ++si)
#pragma unroll
        for (int ni = 0; ni < 2; ++ni)
#pragma unroll
            for (int q = 0; q < 16; ++q) acc[si][ni][q] = 0.f;

    float4 br[4];

    auto loadB = [&](int k0) {
#pragma unroll
        for (int i = 0; i < 2; ++i) {
            const int c = tid * 2 + i;
            const int row = c >> 2, g = c & 3;
            int n = n0 + row; if (n >= N) n = N - 1;
            const float* s = Wf + (size_t)n * K + k0 + g * 8;
            br[2 * i]     = *(const float4*)s;
            br[2 * i + 1] = *(const float4*)(s + 4);
        }
    };
    auto writeB = [&](int buf) {
#pragma unroll
        for (int i = 0; i < 2; ++i) {
            const int c = tid * 2 + i;
            const int row = c >> 2, g = c & 3;
            const int gp = g ^ ((row >> 1) & 3);
            u16x8 H, L;
            const float* f = (const float*)&br[2 * i];
#pragma unroll
            for (int e = 0; e < 8; ++e) {
                u16 hh = f2bf(f[e]);
                H[e] = hh;
                L[e] = f2bf(f[e] - bf2f(hh));
            }
            *(u16x8*)&lB[buf][0][row][gp * 8] = H;
            *(u16x8*)&lB[buf][1][row][gp * 8] = L;
        }
    };
    auto stageA = [&](int buf, int k0) {
#pragma unroll
        for (int h = 0; h < 2; ++h) {
            const int rb = 32 * w + 16 * h;
            const int r = rb + srow;
            const int gk = k0 + ((sslot ^ ((r >> 1) & 3)) << 3);
            const size_t ao = (size_t)(m0 + r) * K + gk;
            gload16(Ah + ao, &lA[buf][0][rb][0]);
            gload16(Al + ao, &lA[buf][1][rb][0]);
        }
    };

    loadB(0);
    stageA(0, 0);
    writeB(0);
    __syncthreads();

    const int nk = K >> 5;
    for (int t = 0; t < nk; ++t) {
        const int buf = t & 1;
        if (t + 1 < nk) { loadB((t + 1) << 5); stageA(buf ^ 1, (t + 1) << 5); }
#pragma unroll
        for (int kh = 0; kh < 2; ++kh) {
            const int k8 = lk + 2 * kh;
            bf16x8_t aH[2], aL[2], bH[2], bL[2];
#pragma unroll
            for (int si = 0; si < 2; ++si) {
                const int r = wm + si * 32 + lr;
                const int sl = (k8 ^ ((r >> 1) & 3)) << 3;
                aH[si] = *(const bf16x8_t*)&lA[buf][0][r][sl];
                aL[si] = *(const bf16x8_t*)&lA[buf][1][r][sl];
            }
#pragma unroll
            for (int ni = 0; ni < 2; ++ni) {
                const int r = wn + ni * 32 + lr;
                const int sl = (k8 ^ ((r >> 1) & 3)) << 3;
                bH[ni] = *(const bf16x8_t*)&lB[buf][0][r][sl];
                bL[ni] = *(const bf16x8_t*)&lB[buf][1][r][sl];
            }
#pragma unroll
            for (int si = 0; si < 2; ++si)
#pragma unroll
                for (int ni = 0; ni < 2; ++ni) {
                    acc[si][ni] = __builtin_amdgcn_mfma_f32_32x32x16_bf16(aH[si], bH[ni], acc[si][ni], 0, 0, 0);
                    acc[si][ni] = __builtin_amdgcn_mfma_f32_32x32x16_bf16(aH[si], bL[ni], acc[si][ni], 0, 0, 0);
                    acc[si][ni] = __builtin_amdgcn_mfma_f32_32x32x16_bf16(aL[si], bH[ni], acc[si][ni], 0, 0, 0);
                }
        }
        if (t + 1 < nk) writeB(buf ^ 1);
        __syncthreads();
    }

    const int rbase = 4 * lk;
#pragma unroll
    for (int si = 0; si < 2; ++si)
#pragma unroll
        for (int ni = 0; ni < 2; ++ni) {
            const int n = n0 + wn + ni * 32 + lr;
            if (n >= N) continue;
            const float bias = b1 ? b1[n] : 0.f;
#pragma unroll
            for (int q = 0; q < 16; ++q) {
                const int m = m0 + wm + si * 32 + (q & 3) + 8 * (q >> 2) + rbase;
                C[(size_t)m * N + n] = acc[si][ni][q] + bias;
            }
        }
}

// ---------------------------------------------------- fp32 128x128 GEMM (Xp only)
__global__ __launch_bounds__(256, 2) void gemm128_wt(
    const float* __restrict__ A, const float* __restrict__ A2, int K1, int K,
    const float* __restrict__ W,
    const float* __restrict__ b1, const float* __restrict__ b2,
    float* __restrict__ C, int M, int N, int act) {
    __shared__ float As[16][132];
    __shared__ float Ws[16][132];
    const int tid = threadIdx.x;
    const int m0 = blockIdx.y * 128;
    const int n0 = blockIdx.x * 128;
    const int lr = tid >> 2;
    const int lc = (tid & 3) << 2;
    const int ty = tid >> 4;
    const int tx = tid & 15;
    float acc[2][2][4][4] = {{{{0.f}}}};
    for (int kc = 0; kc < K; kc += 16) {
        const int k = kc + lc;
#pragma unroll
        for (int h = 0; h < 2; ++h) {
            const int r = lr + 64 * h;
            float4 av;
            if (k < K1) av = *(const float4*)(A + (size_t)(m0 + r) * K1 + k);
            else        av = *(const float4*)(A2 + (size_t)(m0 + r) * (K - K1) + (k - K1));
            As[lc + 0][r] = av.x; As[lc + 1][r] = av.y;
            As[lc + 2][r] = av.z; As[lc + 3][r] = av.w;
            const int n = n0 + r;
            float4 wv = make_float4(0.f, 0.f, 0.f, 0.f);
            if (n < N) wv = *(const float4*)(W + (size_t)n * K + k);
            Ws[lc + 0][r] = wv.x; Ws[lc + 1][r] = wv.y;
            Ws[lc + 2][r] = wv.z; Ws[lc + 3][r] = wv.w;
        }
        __syncthreads();
#pragma unroll
        for (int kt = 0; kt < 16; ++kt) {
            float a[2][4], b[2][4];
            *(float4*)a[0] = *(const float4*)&As[kt][ty << 2];
            *(float4*)a[1] = *(const float4*)&As[kt][64 + (ty << 2)];
            *(float4*)b[0] = *(const float4*)&Ws[kt][tx << 2];
            *(float4*)b[1] = *(const float4*)&Ws[kt][64 + (tx << 2)];
#pragma unroll
            for (int rg = 0; rg < 2; ++rg)
#pragma unroll
                for (int cg = 0; cg < 2; ++cg)
#pragma unroll
                    for (int i = 0; i < 4; ++i)
#pragma unroll
                        for (int j = 0; j < 4; ++j)
                            acc[rg][cg][i][j] = fmaf(a[rg][i], b[cg][j], acc[rg][cg][i][j]);
        }
        __syncthreads();
    }
#pragma unroll
    for (int rg = 0; rg < 2; ++rg)
#pragma unroll
    for (int i = 0; i < 4; ++i) {
        const int m = m0 + rg * 64 + (ty << 2) + i;
#pragma unroll
        for (int cg = 0; cg < 2; ++cg) {
            const int nbase = n0 + cg * 64 + (tx << 2);
            float4 v;
            float* vp = (float*)&v;
#pragma unroll
            for (int j = 0; j < 4; ++j) {
                int n = nbase + j;
                float x = acc[rg][cg][i][j];
                if (n < N) {
                    if (b1) x += b1[n];
                    if (b2) x += b2[n];
                    if (act == 1) x = tanhf(x);
                }
                vp[j] = x;
            }
            if (nbase + 3 < N) {
                *(float4*)(C + (size_t)m * N + nbase) = v;
            } else {
                for (int j = 0; j < 4; ++j)
                    if (nbase + j < N) C[(size_t)m * N + nbase + j] = vp[j];
            }
        }
    }
}

// ------------------------------------------------ poison enc + encFast
__global__ __launch_bounds__(256) void poison_k(float* __restrict__ p) {
    int i = blockIdx.x * 256 + threadIdx.x;      // over 16,777,216 / 4
    uint4 v = make_uint4(POISON, POISON, POISON, POISON);
    *(uint4*)(p + (size_t)i * 4) = *(uint4*)&v;
}

// ------------------------------------------------------------------------------
// Persistent encoder LSTM v5: 256 blocks = 8 groups x 32 j-slices; group =
// blockIdx & 7 -> all 32 blocks of a group on ONE XCD (round-robin dispatch),
// sharing that XCD's L2.  Exchange: producers dual-store h (plain/workgroup ->
// local L2 "encFast", agent -> L3 "enc"); consumers poll encFast with
// buffer_load sc0 (bypass L1, HIT L2) — ~5x lower latency than L3.  If the
// XCD mapping assumption fails, bounded fast-spin falls back to the proven
// agent-scope poll on enc (correct on any placement; no hang).
// Block: 4 batches x 16 j.  Thread: one gate-row dot (gate=tid>>6, bb=tid&3,
// jj=(tid>>2)&15).  tid<64 finalizes; c in registers.
// ------------------------------------------------------------------------------
__global__ __launch_bounds__(256) void enc_persist_k(
    const float* __restrict__ Xg, const float* __restrict__ Whh,
    float* __restrict__ enc, float* __restrict__ encFast)
{
    __shared__ float hlds[4][520];     // 4 batches x 512 (+8 pad)
    __shared__ float pw[4][4][16];     // [gate][bb][jj]
    const int tid = threadIdx.x;
    const int g = blockIdx.x & 7;      // group -> XCD (heuristic)
    const int s = blockIdx.x >> 3;     // j-slice 0..31
    const int j0 = s * 16;
    const int bb = tid & 3;
    const int jj = (tid >> 2) & 15;
    const int gate = tid >> 6;         // 0..3  (i,f,g,o row blocks)
    const float* Wr = Whh + (size_t)(gate * 512 + j0 + jj) * Hz;
    const u32x4_t srsrc = make_srsrc(encFast, 32u * 512u * 512u * 4u);
    const bool ownt = ((tid & 63) >> 1) == s;   // thread's poll chunk is own-slice
    const int hb = tid >> 6;                    // poll batch  (same as gate)
    const int off = (tid * 8) & 511;            // poll column base
    float c_reg = 0.f;                          // tid<64: cell state (bb, j0+jj)

    for (int t = 0; t < Tz; ++t) {
        // xg gather (independent of h; hides under poll)
        float xv0 = 0.f, xv1 = 0.f, xv2 = 0.f, xv3 = 0.f;
        if (tid < 64) {
            const int b2 = tid & 3, j2 = tid >> 2;
            const float* xp = Xg + ((size_t)(4 * g + b2) * Tz + t) * 2048 + j0 + j2;
            xv0 = xp[0]; xv1 = xp[512]; xv2 = xp[1024]; xv3 = xp[1536];
        }

        if (t > 0) {
            if (!ownt) {
                const unsigned voff = (((unsigned)(t - 1) * 32u + 4u * (unsigned)g) * 512u
                                       + (unsigned)tid * 8u) * 4u;
                float4 va, vb;
                bool done = false;
                for (int r = 0; r < 64; ++r) {
                    asm volatile(
                        "buffer_load_dwordx4 %0, %2, %4, 0 offen sc0\n\t"
                        "buffer_load_dwordx4 %1, %3, %4, 0 offen sc0\n\t"
                        "s_waitcnt vmcnt(0)"
                        : "=&v"(va), "=&v"(vb)
                        : "v"(voff), "v"(voff + 16u), "s"(srsrc)
                        : "memory");
                    if (__float_as_uint(va.x) != POISON && __float_as_uint(va.y) != POISON &&
                        __float_as_uint(va.z) != POISON && __float_as_uint(va.w) != POISON &&
                        __float_as_uint(vb.x) != POISON && __float_as_uint(vb.y) != POISON &&
                        __float_as_uint(vb.z) != POISON && __float_as_uint(vb.w) != POISON) {
                        done = true; break;
                    }
                    __builtin_amdgcn_s_sleep(1);
                }
                if (done) {
                    *(float4*)&hlds[hb][off]     = va;
                    *(float4*)&hlds[hb][off + 4] = vb;
                } else {
                    // agent-scope fallback on enc (guaranteed progress, any placement)
                    const float* eb = enc + ((size_t)(4 * g + hb) * Tz + (t - 1)) * Hz + off;
                    float vv[8];
                    unsigned pend = 0xffu;
                    while (pend) {
#pragma unroll
                        for (int e = 0; e < 8; ++e)
                            if (pend & (1u << e))
                                vv[e] = __hip_atomic_load(eb + e, __ATOMIC_RELAXED,
                                                          __HIP_MEMORY_SCOPE_AGENT);
#pragma unroll
                        for (int e = 0; e < 8; ++e)
                            if ((pend & (1u << e)) && __float_as_uint(vv[e]) != POISON) {
                                hlds[hb][off + e] = vv[e];
                                pend &= ~(1u << e);
                            }
                        if (pend) __builtin_amdgcn_s_sleep(4);
                    }
                }
            }
            __syncthreads();
            // one gate-row dot: 512 MAC
            float acc = 0.f;
#pragma unroll 8
            for (int k = 0; k < Hz; k += 4) {
                float4 w4 = *(const float4*)(Wr + k);
                float4 h4 = *(const float4*)&hlds[bb][k];
                acc = fmaf(w4.x, h4.x, acc);
                acc = fmaf(w4.y, h4.y, acc);
                acc = fmaf(w4.z, h4.z, acc);
                acc = fmaf(w4.w, h4.w, acc);
            }
            pw[gate][bb][jj] = acc;
        } else {
            pw[gate][bb][jj] = 0.f;
        }
        __syncthreads();

        if (tid < 64) {
            const int b2 = tid & 3, j2 = tid >> 2;
            float gi = pw[0][b2][j2] + xv0;
            float gf = pw[1][b2][j2] + xv1;
            float gG = pw[2][b2][j2] + xv2;
            float go = pw[3][b2][j2] + xv3;
            float ig = sigf(gi), fg = sigf(gf), G = tanhf(gG), og = sigf(go);
            c_reg = fg * c_reg + ig * G;
            float hn = og * tanhf(c_reg);
            hlds[b2][j0 + j2] = hn;                       // own-slice shortcut
            __hip_atomic_store(encFast + (size_t)t * 16384 + (4 * g + b2) * 512 + j0 + j2,
                               hn, __ATOMIC_RELAXED, __HIP_MEMORY_SCOPE_WORKGROUP);
            __hip_atomic_store(enc + ((size_t)(4 * g + b2) * Tz + t) * Hz + j0 + j2,
                               hn, __ATOMIC_RELAXED, __HIP_MEMORY_SCOPE_AGENT);
        }
        // next iteration's poll writes only non-own hlds columns; its
        // pre-compute barrier orders these finalize writes for all threads.
    }
}

// ---------------------------- positional LSTM + mu_w/sig + mu scan (single block)
__global__ __launch_bounds__(640) void pos_k(const float* __restrict__ Xp,
                                             const float* __restrict__ Wphh,
                                             const float* __restrict__ Wmu,
                                             const float* __restrict__ bmu,
                                             const float* __restrict__ Wsig,
                                             const float* __restrict__ bsig,
                                             float* __restrict__ muv,
                                             float* __restrict__ sgv) {
    __shared__ float hs[Bz][Pz];
    __shared__ float ws[80][Pz];
    __shared__ float mw[Bz][4];
    __shared__ float muprev[Bz];
    __shared__ float wmu_s[4][Pz];
    const int tid = threadIdx.x;
    for (int i = tid; i < 80 * Pz; i += 640) ws[i / Pz][i % Pz] = Wphh[i];
    for (int i = tid; i < 3 * Pz; i += 640) wmu_s[i / Pz][i % Pz] = Wmu[i];
    if (tid < Pz) wmu_s[3][tid] = Wsig[tid];
    if (tid < Bz) muprev[tid] = 0.f;
    const int b = tid / Pz;
    const int p = tid % Pz;
    float c_r = 0.f;
    hs[b][p] = 0.f;
    __syncthreads();
    for (int t = 0; t < Tz; ++t) {
        const float* xp = Xp + ((size_t)b * Tz + t) * 80;
        float a0 = xp[p], a1 = xp[20 + p], a2 = xp[40 + p], a3 = xp[60 + p];
#pragma unroll
        for (int k = 0; k < Pz; ++k) {
            float hk = hs[b][k];
            a0 += ws[p][k] * hk;
            a1 += ws[20 + p][k] * hk;
            a2 += ws[40 + p][k] * hk;
            a3 += ws[60 + p][k] * hk;
        }
        float ig = sigf(a0), fg = sigf(a1), gg = tanhf(a2), og = sigf(a3);
        c_r = fg * c_r + ig * gg;
        float hn = og * tanhf(c_r);
        __syncthreads();
        hs[b][p] = hn;
        __syncthreads();
        if (tid < 128) {
            int bb = tid >> 2, o = tid & 3;
            float s = (o < 3) ? bmu[o] : bsig[0];
#pragma unroll
            for (int k = 0; k < Pz; ++k) s += wmu_s[o][k] * hs[bb][k];
            mw[bb][o] = s;
        }
        __syncthreads();
        if (tid < Bz) {
            float w0 = fmaxf(mw[tid][0], 0.f);
            float w1 = fmaxf(mw[tid][1], 0.f);
            float w2 = fmaxf(mw[tid][2], 0.f);
            float m = w0 * muprev[tid] + w1 * (1.f / 512.f) + w2 * (t + 1.f) / 512.f;
            muprev[tid] = m;
            muv[tid * Tz + t] = m;
            sgv[tid * Tz + t] = sigf(mw[tid][3]);
        }
        __syncthreads();
    }
}

// ---------------------- attention weights, L2-normalized rows, split bf16 output
__global__ __launch_bounds__(256) void attw_k(const float* __restrict__ muv,
                                              const float* __restrict__ sgv,
                                              u16* __restrict__ wH,
                                              u16* __restrict__ wL) {
    const int row = blockIdx.x * 4 + (threadIdx.x >> 6);
    const int lane = threadIdx.x & 63;
    const int b = row >> 9, j = row & 511;
    const float m = muv[b * Tz + j];
    const float s = sgv[b * Tz + j];
    const float inv = 0.5f / (s * s);
    const float rj = 1.0f / (j + 1.0f);
    float vals[8];
    float ss = 0.f;
#pragma unroll
    for (int i = 0; i < 8; ++i) {
        int t = lane + i * 64;
        float v = 0.f;
        if (t <= j) {
            float d = t * rj - m;
            v = expf(-d * d * inv);
        }
        vals[i] = v;
        ss += v * v;
    }
    for (int off = 32; off; off >>= 1) ss += __shfl_xor(ss, off);
    float nrm = 1.0f / fmaxf(sqrtf(ss), 1e-12f);
    u16* rH = wH + (size_t)row * Tz;
    u16* rL = wL + (size_t)row * Tz;
#pragma unroll
    for (int i = 0; i < 8; ++i) {
        float v = vals[i] * nrm;
        u16 h = f2bf(v);
        rH[lane + i * 64] = h;
        rL[lane + i * 64] = f2bf(v - bf2f(h));
    }
}

// ---------------------------------------------------------------------------------
extern "C" void kernel_launch(void* const* d_in, const int* in_sizes, int n_in,
                              void* d_out, int out_size, void* d_ws, size_t ws_size,
                              hipStream_t stream) {
    const int*   inp      = (const int*)d_in[0];
    const float* etab     = (const float*)d_in[3];
    const float* dec_bias = (const float*)d_in[4];
    const float* W_ih     = (const float*)d_in[5];
    const float* W_hh     = (const float*)d_in[6];
    const float* b_ih     = (const float*)d_in[7];
    const float* b_hh     = (const float*)d_in[8];
    const float* Wp_ih    = (const float*)d_in[9];
    const float* Wp_hh    = (const float*)d_in[10];
    const float* bp_ih    = (const float*)d_in[11];
    const float* bp_hh    = (const float*)d_in[12];
    const float* W_mu     = (const float*)d_in[13];
    const float* b_mu     = (const float*)d_in[14];
    const float* W_sig    = (const float*)d_in[15];
    const float* b_sig    = (const float*)d_in[16];
    const float* W_cat    = (const float*)d_in[17];
    const float* b_cat    = (const float*)d_in[18];

    float* out = (float*)d_out;
    // All transients inside d_out (163.84M floats); dead before decoder rewrite.
    float* Xg      = out;                           // 33,554,432 f
    float* enc     = out + 33554432;                //  8,388,608  [b][t][h]
    float* encFast = out + 41943040;                //  8,388,608  [t][b][h]
    float* Xp      = out + 50331648;                //  1,310,720
    float* muv     = out + 51642368;                //     16,384
    float* sgv     = out + 51658752;                //     16,384
    u16*  embH   = (u16*)(out + 51675136);          // 16384x512
    u16*  embL   = (u16*)(out + 55869440);
    u16*  WihH   = (u16*)(out + 60063744);          // 2048x512
    u16*  WihL   = (u16*)(out + 60588032);
    u16*  WcatH  = (u16*)(out + 61112320);          // 512x1024
    u16*  WcatL  = (u16*)(out + 61374464);
    u16*  catH   = (u16*)(out + 61636608);          // 16384x1024
    u16*  catL   = (u16*)(out + 70025216);
    u16*  attwH  = (u16*)(out + 78413824);          // 32x512x512
    u16*  attwL  = (u16*)(out + 82608128);
    u16*  encTH  = (u16*)(out + 86802432);          // 32x512x512
    u16*  encTL  = (u16*)(out + 90996736);          // end 95,191,040 < 163,840,000

    u16* combH = (u16*)d_ws;                        // 16384x512 u16
    u16* combL = (u16*)((char*)d_ws + 16777216);    // 33,554,432 B total (proven)

    // 1. poison enc + encFast (contiguous 16.7M floats) + input splits
    poison_k<<<16384, 256, 0, stream>>>(enc);
    embed_split_k<<<8192, 256, 0, stream>>>(inp, etab, embH, embL);
    split_k<<<1024, 256, 0, stream>>>(W_ih, WihH, WihL, 2048 * 128, 128, 512, 0);
    split_k<<<512, 256, 0, stream>>>(W_cat, WcatH, WcatL, 512 * 256, 256, 1024, 0);

    // 2. Xg = emb @ W_ih^T + b_ih + b_hh  (MFMA split, fp32 out)
    gemm_mfma_split<<<dim3(16, 128), 256, 0, stream>>>(
        embH, embL, WihH, WihL, b_ih, b_hh, Xg, nullptr, nullptr,
        16384, 2048, 512, 0, 0, 0, 0, 0, 0);

    // 3. encoder recurrence — persistent, single-XCD groups, L2 exchange
    enc_persist_k<<<256, 256, 0, stream>>>(Xg, W_hh, enc, encFast);

    // 4. enc -> cat cols [512,1024); enc -> encT H/L
    split_k<<<8192, 256, 0, stream>>>(enc, catH, catL, 16384 * 128, 128, 1024, 512);
    tsplit_k<<<dim3(8, 8, 32), 256, 0, stream>>>(enc, encTH, encTL);

    // 5. Xp = enc @ Wp_ih^T + biases (fp32, N=80)
    gemm128_wt<<<dim3(1, 128), 256, 0, stream>>>(enc, nullptr, 512, 512, Wp_ih, bp_ih, bp_hh,
                                                 Xp, 16384, 80, 0);
    // 6. positional LSTM + heads + mu scan
    pos_k<<<1, 640, 0, stream>>>(Xp, Wp_hh, W_mu, b_mu, W_sig, b_sig, muv, sgv);
    // 7. attention weights -> bf16 split
    attw_k<<<4096, 256, 0, stream>>>(muv, sgv, attwH, attwL);

    // 8. ctx = attw @ encT^T (batched MFMA) -> cat cols [0,512) split bf16
    gemm_mfma_split<<<dim3(4, 4, 32), 256, 0, stream>>>(
        attwH, attwL, encTH, encTL, nullptr, nullptr, nullptr, catH, catL,
        512, 512, 512, 3, (long)512 * 512, (long)512 * 512, 512, 1024, 0);

    // 9. comb = tanh(cat @ W_cat^T + b_cat) -> split bf16 into ws
    gemm_mfma_split<<<dim3(4, 128), 256, 0, stream>>>(
        catH, catL, WcatH, WcatL, b_cat, nullptr, nullptr, combH, combL,
        16384, 512, 1024, 2, 0, 0, 0, 512, 0);

    // 10. decoded = comb @ embedding^T + dec_bias
    gemm_dec<<<dim3(79, 128), 256, 0, stream>>>(
        combH, combL, etab, dec_bias, out, 16384, 10000, 512);
}

// Round 10
// 7693.249 us; speedup vs baseline: 1.4611x; 1.4611x over previous
//
#include <hip/hip_runtime.h>
#include <math.h>

#define Vz 10000
#define Bz 32
#define Tz 512
#define Hz 512
#define Pz 20
#define POISON 0x7fc00001u

typedef unsigned short u16;
typedef unsigned long long u64;
typedef __attribute__((ext_vector_type(8)))  short bf16x8_t;   // 8 bf16 = 4 VGPR
typedef __attribute__((ext_vector_type(8)))  unsigned short u16x8;
typedef __attribute__((ext_vector_type(16))) float f32x16_t;   // 32x32 acc frag
typedef __attribute__((ext_vector_type(4)))  float f32x4_t;

__device__ __forceinline__ float sigf(float x) { return 1.0f / (1.0f + expf(-x)); }

__device__ __forceinline__ u16 f2bf(float x) {           // round-to-nearest-even
    unsigned u = __float_as_uint(x);
    u += 0x7fff + ((u >> 16) & 1);
    return (u16)(u >> 16);
}
__device__ __forceinline__ float bf2f(u16 h) {
    return __uint_as_float(((unsigned)h) << 16);
}

__device__ __forceinline__ void gload16(const u16* g, const u16* l) {
    __builtin_amdgcn_global_load_lds(
        (const __attribute__((address_space(1))) void*)g,
        (__attribute__((address_space(3))) void*)l, 16, 0, 0);
}

// ---------------------------------------------------------------- splitters
__global__ __launch_bounds__(256) void split_k(const float* __restrict__ src,
                                               u16* __restrict__ dH, u16* __restrict__ dL,
                                               int total4, int srcW4, int dstStride, int colOff) {
    int i = blockIdx.x * 256 + threadIdx.x;
    if (i >= total4) return;
    int row = i / srcW4;
    int c4 = (i - row * srcW4) << 2;
    float4 v = *(const float4*)(src + (size_t)row * ((size_t)srcW4 << 2) + c4);
    ushort4 H, L;
    H.x = f2bf(v.x); L.x = f2bf(v.x - bf2f(H.x));
    H.y = f2bf(v.y); L.y = f2bf(v.y - bf2f(H.y));
    H.z = f2bf(v.z); L.z = f2bf(v.z - bf2f(H.z));
    H.w = f2bf(v.w); L.w = f2bf(v.w - bf2f(H.w));
    size_t d = (size_t)row * dstStride + colOff + c4;
    *(ushort4*)(dH + d) = H;
    *(ushort4*)(dL + d) = L;
}

__global__ __launch_bounds__(256) void embed_split_k(const int* __restrict__ inp,
                                                     const float* __restrict__ etab,
                                                     u16* __restrict__ dH, u16* __restrict__ dL) {
    int i = blockIdx.x * 256 + threadIdx.x;
    int row = i >> 7;
    int c4 = (i & 127) << 2;
    float4 v = *(const float4*)(etab + (size_t)inp[row] * Hz + c4);
    ushort4 H, L;
    H.x = f2bf(v.x); L.x = f2bf(v.x - bf2f(H.x));
    H.y = f2bf(v.y); L.y = f2bf(v.y - bf2f(H.y));
    H.z = f2bf(v.z); L.z = f2bf(v.z - bf2f(H.z));
    H.w = f2bf(v.w); L.w = f2bf(v.w - bf2f(H.w));
    size_t d = (size_t)row * Hz + c4;
    *(ushort4*)(dH + d) = H;
    *(ushort4*)(dL + d) = L;
}

// per-batch transpose + split: enc[b][t][h] -> encT H/L [b][h][t]
__global__ __launch_bounds__(256) void tsplit_k(const float* __restrict__ enc,
                                                u16* __restrict__ dH, u16* __restrict__ dL) {
    __shared__ float ls[64][65];
    const int b = blockIdx.z;
    const int t0 = blockIdx.y * 64;
    const int h0 = blockIdx.x * 64;
    const int tid = threadIdx.x;
    const int rr = tid >> 4;
    const int cc = (tid & 15) << 2;
    const float* eb = enc + (size_t)b * Tz * Hz;
#pragma unroll
    for (int i = 0; i < 4; ++i) {
        int t = rr + i * 16;
        float4 v = *(const float4*)(eb + (size_t)(t0 + t) * Hz + h0 + cc);
        ls[t][cc] = v.x; ls[t][cc + 1] = v.y; ls[t][cc + 2] = v.z; ls[t][cc + 3] = v.w;
    }
    __syncthreads();
    u16* oH = dH + (size_t)b * Tz * Hz;
    u16* oL = dL + (size_t)b * Tz * Hz;
#pragma unroll
    for (int i = 0; i < 4; ++i) {
        int h = rr + i * 16;
        float x0 = ls[cc + 0][h], x1 = ls[cc + 1][h], x2 = ls[cc + 2][h], x3 = ls[cc + 3][h];
        ushort4 H, L;
        H.x = f2bf(x0); L.x = f2bf(x0 - bf2f(H.x));
        H.y = f2bf(x1); L.y = f2bf(x1 - bf2f(H.y));
        H.z = f2bf(x2); L.z = f2bf(x2 - bf2f(H.z));
        H.w = f2bf(x3); L.w = f2bf(x3 - bf2f(H.w));
        size_t d = (size_t)(h0 + h) * Tz + t0 + cc;
        *(ushort4*)(oH + d) = H;
        *(ushort4*)(oL + d) = L;
    }
}

// ------------------------------------------------------------------------------
// bf16x2-split MFMA GEMM (validated rounds 2-9):  C = act(A @ W^T + b1 + b2)
// ------------------------------------------------------------------------------
__device__ __forceinline__ void stage_tiles(const u16 (*L)[128][32],
    const u16* __restrict__ Ah, const u16* __restrict__ Al,
    const u16* __restrict__ Wh, const u16* __restrict__ Wl,
    int m0, int n0, int N, int K, int k0, int w, int l)
{
    const int srow = l >> 2, sslot = l & 3;
#pragma unroll
    for (int h = 0; h < 2; ++h) {
        const int rb = 32 * w + 16 * h;
        const int r = rb + srow;
        const int xr = (r >> 1) & 3;
        const int gk = k0 + ((sslot ^ xr) << 3);
        const size_t ao = (size_t)(m0 + r) * K + gk;
        int nrow = n0 + r; if (nrow >= N) nrow = N - 1;
        const size_t wo = (size_t)nrow * K + gk;
        gload16(Ah + ao, &L[0][rb][0]);
        gload16(Al + ao, &L[1][rb][0]);
        gload16(Wh + wo, &L[2][rb][0]);
        gload16(Wl + wo, &L[3][rb][0]);
    }
}

__global__ __launch_bounds__(256, 2) void gemm_mfma_split(
    const u16* __restrict__ Ah_, const u16* __restrict__ Al_,
    const u16* __restrict__ Wh_, const u16* __restrict__ Wl_,
    const float* __restrict__ b1, const float* __restrict__ b2,
    float* __restrict__ C, u16* __restrict__ CH, u16* __restrict__ CL,
    int M, int N, int K, int omode,
    long bsA, long bsW, int bsCrows, int cstride, int coff)
{
    __shared__ u16 lds[2][4][128][32];
    const int z = blockIdx.z;
    const u16* Ah = Ah_ + (size_t)z * bsA;
    const u16* Al = Al_ + (size_t)z * bsA;
    const u16* Wh = Wh_ + (size_t)z * bsW;
    const u16* Wl = Wl_ + (size_t)z * bsW;
    const int crow0 = z * bsCrows;
    const int tid = threadIdx.x;
    const int w = tid >> 6;
    const int l = tid & 63;
    const int m0 = blockIdx.y * 128;
    const int n0 = blockIdx.x * 128;
    const int wm = (w >> 1) * 64;
    const int wn = (w & 1) * 64;
    const int lr = l & 31;
    const int lk = l >> 5;

    f32x16_t acc[2][2];
#pragma unroll
    for (int si = 0; si < 2; ++si)
#pragma unroll
        for (int ni = 0; ni < 2; ++ni)
#pragma unroll
            for (int q = 0; q < 16; ++q) acc[si][ni][q] = 0.f;

    const int nk = K >> 5;
    stage_tiles(lds[0], Ah, Al, Wh, Wl, m0, n0, N, K, 0, w, l);
    __syncthreads();

    for (int t = 0; t < nk; ++t) {
        const int buf = t & 1;
        if (t + 1 < nk)
            stage_tiles(lds[buf ^ 1], Ah, Al, Wh, Wl, m0, n0, N, K, (t + 1) << 5, w, l);
        const u16 (*L)[128][32] = lds[buf];
#pragma unroll
        for (int kh = 0; kh < 2; ++kh) {
            const int k8 = lk + 2 * kh;
            bf16x8_t aH[2], aL[2], bH[2], bL[2];
#pragma unroll
            for (int si = 0; si < 2; ++si) {
                const int r = wm + si * 32 + lr;
                const int sl = (k8 ^ ((r >> 1) & 3)) << 3;
                aH[si] = *(const bf16x8_t*)&L[0][r][sl];
                aL[si] = *(const bf16x8_t*)&L[1][r][sl];
            }
#pragma unroll
            for (int ni = 0; ni < 2; ++ni) {
                const int r = wn + ni * 32 + lr;
                const int sl = (k8 ^ ((r >> 1) & 3)) << 3;
                bH[ni] = *(const bf16x8_t*)&L[2][r][sl];
                bL[ni] = *(const bf16x8_t*)&L[3][r][sl];
            }
#pragma unroll
            for (int si = 0; si < 2; ++si)
#pragma unroll
                for (int ni = 0; ni < 2; ++ni) {
                    acc[si][ni] = __builtin_amdgcn_mfma_f32_32x32x16_bf16(aH[si], bH[ni], acc[si][ni], 0, 0, 0);
                    acc[si][ni] = __builtin_amdgcn_mfma_f32_32x32x16_bf16(aH[si], bL[ni], acc[si][ni], 0, 0, 0);
                    acc[si][ni] = __builtin_amdgcn_mfma_f32_32x32x16_bf16(aL[si], bH[ni], acc[si][ni], 0, 0, 0);
                }
        }
        __syncthreads();
    }

    const int rbase = 4 * lk;
#pragma unroll
    for (int si = 0; si < 2; ++si)
#pragma unroll
        for (int ni = 0; ni < 2; ++ni) {
            const int n = n0 + wn + ni * 32 + lr;
            if (n >= N) continue;
            const float bias = (b1 ? b1[n] : 0.f) + (b2 ? b2[n] : 0.f);
#pragma unroll
            for (int q = 0; q < 16; ++q) {
                const int m = m0 + wm + si * 32 + (q & 3) + 8 * (q >> 2) + rbase;
                const int crow = crow0 + m;
                float x = acc[si][ni][q] + bias;
                if (omode == 0) {
                    C[(size_t)crow * N + n] = x;
                } else if (omode == 1) {
                    C[(size_t)crow * N + n] = tanhf(x);
                } else {
                    if (omode == 2) x = tanhf(x);
                    u16 h = f2bf(x);
                    CH[(size_t)crow * cstride + coff + n] = h;
                    CL[(size_t)crow * cstride + coff + n] = f2bf(x - bf2f(h));
                }
            }
        }
}

// ------------------------------------------------------------------------------
// Decoder GEMM (validated round 4): A = combH/L pre-split; W = etab fp32,
// split on the fly into swizzled LDS.
// ------------------------------------------------------------------------------
__global__ __launch_bounds__(256, 2) void gemm_dec(
    const u16* __restrict__ Ah, const u16* __restrict__ Al,
    const float* __restrict__ Wf, const float* __restrict__ b1,
    float* __restrict__ C, int M, int N, int K)
{
    __shared__ u16 lA[2][2][128][32];
    __shared__ u16 lB[2][2][128][32];
    const int tid = threadIdx.x;
    const int w = tid >> 6, l = tid & 63;
    const int m0 = blockIdx.y * 128, n0 = blockIdx.x * 128;
    const int wm = (w >> 1) * 64, wn = (w & 1) * 64;
    const int lr = l & 31, lk = l >> 5;
    const int srow = l >> 2, sslot = l & 3;

    f32x16_t acc[2][2];
#pragma unroll
    for (int si = 0; si < 2; ++si)
#pragma unroll
        for (int ni = 0; ni < 2; ++ni)
#pragma unroll
            for (int q = 0; q < 16; ++q) acc[si][ni][q] = 0.f;

    float4 br[4];

    auto loadB = [&](int k0) {
#pragma unroll
        for (int i = 0; i < 2; ++i) {
            const int c = tid * 2 + i;
            const int row = c >> 2, g = c & 3;
            int n = n0 + row; if (n >= N) n = N - 1;
            const float* s = Wf + (size_t)n * K + k0 + g * 8;
            br[2 * i]     = *(const float4*)s;
            br[2 * i + 1] = *(const float4*)(s + 4);
        }
    };
    auto writeB = [&](int buf) {
#pragma unroll
        for (int i = 0; i < 2; ++i) {
            const int c = tid * 2 + i;
            const int row = c >> 2, g = c & 3;
            const int gp = g ^ ((row >> 1) & 3);
            u16x8 H, L;
            const float* f = (const float*)&br[2 * i];
#pragma unroll
            for (int e = 0; e < 8; ++e) {
                u16 hh = f2bf(f[e]);
                H[e] = hh;
                L[e] = f2bf(f[e] - bf2f(hh));
            }
            *(u16x8*)&lB[buf][0][row][gp * 8] = H;
            *(u16x8*)&lB[buf][1][row][gp * 8] = L;
        }
    };
    auto stageA = [&](int buf, int k0) {
#pragma unroll
        for (int h = 0; h < 2; ++h) {
            const int rb = 32 * w + 16 * h;
            const int r = rb + srow;
            const int gk = k0 + ((sslot ^ ((r >> 1) & 3)) << 3);
            const size_t ao = (size_t)(m0 + r) * K + gk;
            gload16(Ah + ao, &lA[buf][0][rb][0]);
            gload16(Al + ao, &lA[buf][1][rb][0]);
        }
    };

    loadB(0);
    stageA(0, 0);
    writeB(0);
    __syncthreads();

    const int nk = K >> 5;
    for (int t = 0; t < nk; ++t) {
        const int buf = t & 1;
        if (t + 1 < nk) { loadB((t + 1) << 5); stageA(buf ^ 1, (t + 1) << 5); }
#pragma unroll
        for (int kh = 0; kh < 2; ++kh) {
            const int k8 = lk + 2 * kh;
            bf16x8_t aH[2], aL[2], bH[2], bL[2];
#pragma unroll
            for (int si = 0; si < 2; ++si) {
                const int r = wm + si * 32 + lr;
                const int sl = (k8 ^ ((r >> 1) & 3)) << 3;
                aH[si] = *(const bf16x8_t*)&lA[buf][0][r][sl];
                aL[si] = *(const bf16x8_t*)&lA[buf][1][r][sl];
            }
#pragma unroll
            for (int ni = 0; ni < 2; ++ni) {
                const int r = wn + ni * 32 + lr;
                const int sl = (k8 ^ ((r >> 1) & 3)) << 3;
                bH[ni] = *(const bf16x8_t*)&lB[buf][0][r][sl];
                bL[ni] = *(const bf16x8_t*)&lB[buf][1][r][sl];
            }
#pragma unroll
            for (int si = 0; si < 2; ++si)
#pragma unroll
                for (int ni = 0; ni < 2; ++ni) {
                    acc[si][ni] = __builtin_amdgcn_mfma_f32_32x32x16_bf16(aH[si], bH[ni], acc[si][ni], 0, 0, 0);
                    acc[si][ni] = __builtin_amdgcn_mfma_f32_32x32x16_bf16(aH[si], bL[ni], acc[si][ni], 0, 0, 0);
                    acc[si][ni] = __builtin_amdgcn_mfma_f32_32x32x16_bf16(aL[si], bH[ni], acc[si][ni], 0, 0, 0);
                }
        }
        if (t + 1 < nk) writeB(buf ^ 1);
        __syncthreads();
    }

    const int rbase = 4 * lk;
#pragma unroll
    for (int si = 0; si < 2; ++si)
#pragma unroll
        for (int ni = 0; ni < 2; ++ni) {
            const int n = n0 + wn + ni * 32 + lr;
            if (n >= N) continue;
            const float bias = b1 ? b1[n] : 0.f;
#pragma unroll
            for (int q = 0; q < 16; ++q) {
                const int m = m0 + wm + si * 32 + (q & 3) + 8 * (q >> 2) + rbase;
                C[(size_t)m * N + n] = acc[si][ni][q] + bias;
            }
        }
}

// ---------------------------------------------------- fp32 128x128 GEMM (Xp only)
__global__ __launch_bounds__(256, 2) void gemm128_wt(
    const float* __restrict__ A, const float* __restrict__ A2, int K1, int K,
    const float* __restrict__ W,
    const float* __restrict__ b1, const float* __restrict__ b2,
    float* __restrict__ C, int M, int N, int act) {
    __shared__ float As[16][132];
    __shared__ float Ws[16][132];
    const int tid = threadIdx.x;
    const int m0 = blockIdx.y * 128;
    const int n0 = blockIdx.x * 128;
    const int lr = tid >> 2;
    const int lc = (tid & 3) << 2;
    const int ty = tid >> 4;
    const int tx = tid & 15;
    float acc[2][2][4][4] = {{{{0.f}}}};
    for (int kc = 0; kc < K; kc += 16) {
        const int k = kc + lc;
#pragma unroll
        for (int h = 0; h < 2; ++h) {
            const int r = lr + 64 * h;
            float4 av;
            if (k < K1) av = *(const float4*)(A + (size_t)(m0 + r) * K1 + k);
            else        av = *(const float4*)(A2 + (size_t)(m0 + r) * (K - K1) + (k - K1));
            As[lc + 0][r] = av.x; As[lc + 1][r] = av.y;
            As[lc + 2][r] = av.z; As[lc + 3][r] = av.w;
            const int n = n0 + r;
            float4 wv = make_float4(0.f, 0.f, 0.f, 0.f);
            if (n < N) wv = *(const float4*)(W + (size_t)n * K + k);
            Ws[lc + 0][r] = wv.x; Ws[lc + 1][r] = wv.y;
            Ws[lc + 2][r] = wv.z; Ws[lc + 3][r] = wv.w;
        }
        __syncthreads();
#pragma unroll
        for (int kt = 0; kt < 16; ++kt) {
            float a[2][4], b[2][4];
            *(float4*)a[0] = *(const float4*)&As[kt][ty << 2];
            *(float4*)a[1] = *(const float4*)&As[kt][64 + (ty << 2)];
            *(float4*)b[0] = *(const float4*)&Ws[kt][tx << 2];
            *(float4*)b[1] = *(const float4*)&Ws[kt][64 + (tx << 2)];
#pragma unroll
            for (int rg = 0; rg < 2; ++rg)
#pragma unroll
                for (int cg = 0; cg < 2; ++cg)
#pragma unroll
                    for (int i = 0; i < 4; ++i)
#pragma unroll
                        for (int j = 0; j < 4; ++j)
                            acc[rg][cg][i][j] = fmaf(a[rg][i], b[cg][j], acc[rg][cg][i][j]);
        }
        __syncthreads();
    }
#pragma unroll
    for (int rg = 0; rg < 2; ++rg)
#pragma unroll
    for (int i = 0; i < 4; ++i) {
        const int m = m0 + rg * 64 + (ty << 2) + i;
#pragma unroll
        for (int cg = 0; cg < 2; ++cg) {
            const int nbase = n0 + cg * 64 + (tx << 2);
            float4 v;
            float* vp = (float*)&v;
#pragma unroll
            for (int j = 0; j < 4; ++j) {
                int n = nbase + j;
                float x = acc[rg][cg][i][j];
                if (n < N) {
                    if (b1) x += b1[n];
                    if (b2) x += b2[n];
                    if (act == 1) x = tanhf(x);
                }
                vp[j] = x;
            }
            if (nbase + 3 < N) {
                *(float4*)(C + (size_t)m * N + nbase) = v;
            } else {
                for (int j = 0; j < 4; ++j)
                    if (nbase + j < N) C[(size_t)m * N + nbase + j] = vp[j];
            }
        }
    }
}

// ------------------------------------------------ poison enc for data-polling
__global__ __launch_bounds__(256) void poison_k(float* __restrict__ enc) {
    int i = blockIdx.x * 256 + threadIdx.x;      // over 8,388,608 / 4
    uint4 p = make_uint4(POISON, POISON, POISON, POISON);
    *(uint4*)(enc + (size_t)i * 4) = *(uint4*)&p;
}

// ------------------------------------------------------------------------------
// Persistent encoder LSTM v6: 128 blocks = 4 batch-groups x 32 j-slices (the
// round-8 structure) with the poll REWRITTEN as ONE inline-asm block:
// 4 x global_load_dwordx4 sc0 sc1 (L1+L2 bypass -> L3) issued back-to-back,
// ONE s_waitcnt vmcnt(0).  __hip_atomic_load emitted per-word waits serialized
// 16 L3 round trips per poll (~6us); this makes a poll round cost ~1 L3 latency.
// Thread owns 16 contiguous dwords of h[t-1]: lane l of wave w covers rows
// hb=2w,2w+1 at cols [l*4, l*4+4) and [256+l*4, ...).  Retry reloads all 4
// chunks (values are monotonic poison->final, overwrites benign).  Own-slice
// chunks excluded from the check (own h comes via the LDS shortcut).
// ------------------------------------------------------------------------------
__global__ __launch_bounds__(256) void enc_persist_k(
    const float* __restrict__ Xg, const float* __restrict__ Whh,
    float* __restrict__ enc)
{
    __shared__ float hlds[8][516];     // 8 batches x 512 (+4 pad)
    __shared__ float ex[128][2];       // upper gate-pair exchange
    const int tid = threadIdx.x;
    const int g = blockIdx.x >> 5;     // batch group (8 batches)
    const int sidx = blockIdx.x & 31;  // j-slice
    const int j0 = sidx * 16;
    const int bb = tid & 7;
    const int q = tid >> 3;            // 0..31
    const int jj = q & 15;
    const int gp = q >> 4;             // 0: gates i,f   1: gates g,o
    const float* Wr0 = Whh + (size_t)((2 * gp) * 512 + j0 + jj) * Hz;
    const float* Wr1 = Wr0 + (size_t)512 * Hz;

    // poll mapping: wave w, lane l -> rows hb0=2w, hb1=2w+1, col base l*4
    const int wv = tid >> 6, ln = tid & 63;
    const int hb0 = 2 * wv, hb1 = 2 * wv + 1;
    const int cb = ln * 4;                       // 0..252
    const bool need0 = (cb >> 4) != sidx;        // chunks at col cb
    const bool need1 = ((cb >> 4) + 16) != sidx; // chunks at col cb+256
    u64 a0 = (u64)(size_t)(enc + ((size_t)(g * 8 + hb0) * Tz + 0) * Hz + cb);
    u64 a1 = (u64)(size_t)(enc + ((size_t)(g * 8 + hb1) * Tz + 0) * Hz + cb);
    float c_reg = 0.f;                 // tid<128: cell state for (g*8+bb, j0+jj)

    for (int t = 0; t < Tz; ++t) {
        // xg gather (independent of h; overlaps the poll)
        float xv0 = 0.f, xv1 = 0.f, xv2 = 0.f, xv3 = 0.f;
        if (tid < 128) {
            const float* xp = Xg + ((size_t)(g * 8 + bb) * Tz + t) * 2048 + j0 + jj;
            xv0 = xp[0]; xv1 = xp[512]; xv2 = xp[1024]; xv3 = xp[1536];
        }

        float acc0 = 0.f, acc1 = 0.f;
        if (t > 0) {
            f32x4_t v0, v1, v2, v3;
            for (;;) {
                asm volatile(
                    "global_load_dwordx4 %0, %4, off sc0 sc1\n\t"
                    "global_load_dwordx4 %1, %4, off offset:1024 sc0 sc1\n\t"
                    "global_load_dwordx4 %2, %5, off sc0 sc1\n\t"
                    "global_load_dwordx4 %3, %5, off offset:1024 sc0 sc1\n\t"
                    "s_waitcnt vmcnt(0)"
                    : "=&v"(v0), "=&v"(v1), "=&v"(v2), "=&v"(v3)
                    : "v"(a0), "v"(a1)
                    : "memory");
                bool bad = false;
                if (need0) {
                    bad |= (__float_as_uint(v0.x) == POISON) | (__float_as_uint(v0.y) == POISON) |
                           (__float_as_uint(v0.z) == POISON) | (__float_as_uint(v0.w) == POISON) |
                           (__float_as_uint(v2.x) == POISON) | (__float_as_uint(v2.y) == POISON) |
                           (__float_as_uint(v2.z) == POISON) | (__float_as_uint(v2.w) == POISON);
                }
                if (need1) {
                    bad |= (__float_as_uint(v1.x) == POISON) | (__float_as_uint(v1.y) == POISON) |
                           (__float_as_uint(v1.z) == POISON) | (__float_as_uint(v1.w) == POISON) |
                           (__float_as_uint(v3.x) == POISON) | (__float_as_uint(v3.y) == POISON) |
                           (__float_as_uint(v3.z) == POISON) | (__float_as_uint(v3.w) == POISON);
                }
                if (!bad) break;
                __builtin_amdgcn_s_sleep(1);
            }
            if (need0) {
                *(f32x4_t*)&hlds[hb0][cb] = v0;
                *(f32x4_t*)&hlds[hb1][cb] = v2;
            }
            if (need1) {
                *(f32x4_t*)&hlds[hb0][cb + 256] = v1;
                *(f32x4_t*)&hlds[hb1][cb + 256] = v3;
            }
            a0 += 2048; a1 += 2048;              // advance to next t-1
            __syncthreads();
            // dot products: 2 gate rows x 512 k
#pragma unroll 8
            for (int k = 0; k < Hz; k += 4) {
                float4 w0 = *(const float4*)(Wr0 + k);
                float4 w1 = *(const float4*)(Wr1 + k);
                float4 h4 = *(const float4*)&hlds[bb][k];
                acc0 += w0.x * h4.x + w0.y * h4.y + w0.z * h4.z + w0.w * h4.w;
                acc1 += w1.x * h4.x + w1.y * h4.y + w1.z * h4.z + w1.w * h4.w;
            }
        }
        // exchange upper gate pair, finalize
        if (tid >= 128) { ex[tid - 128][0] = acc0; ex[tid - 128][1] = acc1; }
        __syncthreads();
        if (tid < 128) {
            float gi = acc0 + xv0;
            float gf = acc1 + xv1;
            float gg = ex[tid][0] + xv2;
            float go = ex[tid][1] + xv3;
            float ig = sigf(gi), fg = sigf(gf), G = tanhf(gg), og = sigf(go);
            c_reg = fg * c_reg + ig * G;
            float hn = og * tanhf(c_reg);
            hlds[bb][j0 + jj] = hn;                       // own-slice shortcut
            __hip_atomic_store(enc + ((size_t)(g * 8 + bb) * Tz + t) * Hz + j0 + jj, hn,
                               __ATOMIC_RELAXED, __HIP_MEMORY_SCOPE_AGENT);
        }
        // no trailing barrier: next poll writes only non-own hlds cells;
        // its post-poll barrier orders finalize's hlds writes before the dot.
    }
}

// ---------------------------- positional LSTM + mu_w/sig + mu scan (single block)
__global__ __launch_bounds__(640) void pos_k(const float* __restrict__ Xp,
                                             const float* __restrict__ Wphh,
                                             const float* __restrict__ Wmu,
                                             const float* __restrict__ bmu,
                                             const float* __restrict__ Wsig,
                                             const float* __restrict__ bsig,
                                             float* __restrict__ muv,
                                             float* __restrict__ sgv) {
    __shared__ float hs[Bz][Pz];
    __shared__ float ws[80][Pz];
    __shared__ float mw[Bz][4];
    __shared__ float muprev[Bz];
    __shared__ float wmu_s[4][Pz];
    const int tid = threadIdx.x;
    for (int i = tid; i < 80 * Pz; i += 640) ws[i / Pz][i % Pz] = Wphh[i];
    for (int i = tid; i < 3 * Pz; i += 640) wmu_s[i / Pz][i % Pz] = Wmu[i];
    if (tid < Pz) wmu_s[3][tid] = Wsig[tid];
    if (tid < Bz) muprev[tid] = 0.f;
    const int b = tid / Pz;
    const int p = tid % Pz;
    float c_r = 0.f;
    hs[b][p] = 0.f;
    __syncthreads();
    for (int t = 0; t < Tz; ++t) {
        const float* xp = Xp + ((size_t)b * Tz + t) * 80;
        float a0 = xp[p], a1 = xp[20 + p], a2 = xp[40 + p], a3 = xp[60 + p];
#pragma unroll
        for (int k = 0; k < Pz; ++k) {
            float hk = hs[b][k];
            a0 += ws[p][k] * hk;
            a1 += ws[20 + p][k] * hk;
            a2 += ws[40 + p][k] * hk;
            a3 += ws[60 + p][k] * hk;
        }
        float ig = sigf(a0), fg = sigf(a1), gg = tanhf(a2), og = sigf(a3);
        c_r = fg * c_r + ig * gg;
        float hn = og * tanhf(c_r);
        __syncthreads();
        hs[b][p] = hn;
        __syncthreads();
        if (tid < 128) {
            int bb = tid >> 2, o = tid & 3;
            float s = (o < 3) ? bmu[o] : bsig[0];
#pragma unroll
            for (int k = 0; k < Pz; ++k) s += wmu_s[o][k] * hs[bb][k];
            mw[bb][o] = s;
        }
        __syncthreads();
        if (tid < Bz) {
            float w0 = fmaxf(mw[tid][0], 0.f);
            float w1 = fmaxf(mw[tid][1], 0.f);
            float w2 = fmaxf(mw[tid][2], 0.f);
            float m = w0 * muprev[tid] + w1 * (1.f / 512.f) + w2 * (t + 1.f) / 512.f;
            muprev[tid] = m;
            muv[tid * Tz + t] = m;
            sgv[tid * Tz + t] = sigf(mw[tid][3]);
        }
        __syncthreads();
    }
}

// ---------------------- attention weights, L2-normalized rows, split bf16 output
__global__ __launch_bounds__(256) void attw_k(const float* __restrict__ muv,
                                              const float* __restrict__ sgv,
                                              u16* __restrict__ wH,
                                              u16* __restrict__ wL) {
    const int row = blockIdx.x * 4 + (threadIdx.x >> 6);
    const int lane = threadIdx.x & 63;
    const int b = row >> 9, j = row & 511;
    const float m = muv[b * Tz + j];
    const float s = sgv[b * Tz + j];
    const float inv = 0.5f / (s * s);
    const float rj = 1.0f / (j + 1.0f);
    float vals[8];
    float ss = 0.f;
#pragma unroll
    for (int i = 0; i < 8; ++i) {
        int t = lane + i * 64;
        float v = 0.f;
        if (t <= j) {
            float d = t * rj - m;
            v = expf(-d * d * inv);
        }
        vals[i] = v;
        ss += v * v;
    }
    for (int off = 32; off; off >>= 1) ss += __shfl_xor(ss, off);
    float nrm = 1.0f / fmaxf(sqrtf(ss), 1e-12f);
    u16* rH = wH + (size_t)row * Tz;
    u16* rL = wL + (size_t)row * Tz;
#pragma unroll
    for (int i = 0; i < 8; ++i) {
        float v = vals[i] * nrm;
        u16 h = f2bf(v);
        rH[lane + i * 64] = h;
        rL[lane + i * 64] = f2bf(v - bf2f(h));
    }
}

// ---------------------------------------------------------------------------------
extern "C" void kernel_launch(void* const* d_in, const int* in_sizes, int n_in,
                              void* d_out, int out_size, void* d_ws, size_t ws_size,
                              hipStream_t stream) {
    const int*   inp      = (const int*)d_in[0];
    const float* etab     = (const float*)d_in[3];
    const float* dec_bias = (const float*)d_in[4];
    const float* W_ih     = (const float*)d_in[5];
    const float* W_hh     = (const float*)d_in[6];
    const float* b_ih     = (const float*)d_in[7];
    const float* b_hh     = (const float*)d_in[8];
    const float* Wp_ih    = (const float*)d_in[9];
    const float* Wp_hh    = (const float*)d_in[10];
    const float* bp_ih    = (const float*)d_in[11];
    const float* bp_hh    = (const float*)d_in[12];
    const float* W_mu     = (const float*)d_in[13];
    const float* b_mu     = (const float*)d_in[14];
    const float* W_sig    = (const float*)d_in[15];
    const float* b_sig    = (const float*)d_in[16];
    const float* W_cat    = (const float*)d_in[17];
    const float* b_cat    = (const float*)d_in[18];

    float* out = (float*)d_out;
    // All transients inside d_out (163.84M floats); dead before decoder rewrite.
    float*    Xg    = out;                          // 33,554,432 f
    float*    enc   = out + 33554432;               //  8,388,608
    float*    Xp    = out + 41959424;               //  1,310,720
    float*    muv   = out + 43270144;               //     16,384
    float*    sgv   = out + 43286528;               //     16,384
    u16*  embH   = (u16*)(out + 43302912);          // 16384x512
    u16*  embL   = (u16*)(out + 47497216);
    u16*  WihH   = (u16*)(out + 51691520);          // 2048x512
    u16*  WihL   = (u16*)(out + 52215808);
    u16*  WcatH  = (u16*)(out + 52740096);          // 512x1024
    u16*  WcatL  = (u16*)(out + 53002240);
    u16*  catH   = (u16*)(out + 53264384);          // 16384x1024
    u16*  catL   = (u16*)(out + 61652992);
    u16*  attwH  = (u16*)(out + 70041600);          // 32x512x512
    u16*  attwL  = (u16*)(out + 74235904);
    u16*  encTH  = (u16*)(out + 78430208);          // 32x512x512
    u16*  encTL  = (u16*)(out + 82624512);          // end 86,818,816 < 163,840,000

    u16* combH = (u16*)d_ws;                        // 16384x512 u16
    u16* combL = (u16*)((char*)d_ws + 16777216);    // 33,554,432 B total (proven)

    // 1. poison enc (readiness sentinel) + input splits
    poison_k<<<8192, 256, 0, stream>>>(enc);
    embed_split_k<<<8192, 256, 0, stream>>>(inp, etab, embH, embL);
    split_k<<<1024, 256, 0, stream>>>(W_ih, WihH, WihL, 2048 * 128, 128, 512, 0);
    split_k<<<512, 256, 0, stream>>>(W_cat, WcatH, WcatL, 512 * 256, 256, 1024, 0);

    // 2. Xg = emb @ W_ih^T + b_ih + b_hh  (MFMA split, fp32 out)
    gemm_mfma_split<<<dim3(16, 128), 256, 0, stream>>>(
        embH, embL, WihH, WihL, b_ih, b_hh, Xg, nullptr, nullptr,
        16384, 2048, 512, 0, 0, 0, 0, 0, 0);

    // 3. encoder recurrence — persistent, poison polling, asm-batched MLP polls
    enc_persist_k<<<128, 256, 0, stream>>>(Xg, W_hh, enc);

    // 4. enc -> cat cols [512,1024); enc -> encT H/L
    split_k<<<8192, 256, 0, stream>>>(enc, catH, catL, 16384 * 128, 128, 1024, 512);
    tsplit_k<<<dim3(8, 8, 32), 256, 0, stream>>>(enc, encTH, encTL);

    // 5. Xp = enc @ Wp_ih^T + biases (fp32, N=80)
    gemm128_wt<<<dim3(1, 128), 256, 0, stream>>>(enc, nullptr, 512, 512, Wp_ih, bp_ih, bp_hh,
                                                 Xp, 16384, 80, 0);
    // 6. positional LSTM + heads + mu scan
    pos_k<<<1, 640, 0, stream>>>(Xp, Wp_hh, W_mu, b_mu, W_sig, b_sig, muv, sgv);
    // 7. attention weights -> bf16 split
    attw_k<<<4096, 256, 0, stream>>>(muv, sgv, attwH, attwL);

    // 8. ctx = attw @ encT^T (batched MFMA) -> cat cols [0,512) split bf16
    gemm_mfma_split<<<dim3(4, 4, 32), 256, 0, stream>>>(
        attwH, attwL, encTH, encTL, nullptr, nullptr, nullptr, catH, catL,
        512, 512, 512, 3, (long)512 * 512, (long)512 * 512, 512, 1024, 0);

    // 9. comb = tanh(cat @ W_cat^T + b_cat) -> split bf16 into ws
    gemm_mfma_split<<<dim3(4, 128), 256, 0, stream>>>(
        catH, catL, WcatH, WcatL, b_cat, nullptr, nullptr, combH, combL,
        16384, 512, 1024, 2, 0, 0, 0, 512, 0);

    // 10. decoded = comb @ embedding^T + dec_bias
    gemm_dec<<<dim3(79, 128), 256, 0, stream>>>(
        combH, combL, etab, dec_bias, out, 16384, 10000, 512);
}

// Round 11
// 5874.744 us; speedup vs baseline: 1.9133x; 1.3095x over previous
//
#include <hip/hip_runtime.h>
#include <math.h>

#define Vz 10000
#define Bz 32
#define Tz 512
#define Hz 512
#define Pz 20
#define POISON 0x7fc00001u

typedef unsigned short u16;
typedef unsigned long long u64;
typedef __attribute__((ext_vector_type(8)))  short bf16x8_t;   // 8 bf16 = 4 VGPR
typedef __attribute__((ext_vector_type(8)))  unsigned short u16x8;
typedef __attribute__((ext_vector_type(16))) float f32x16_t;   // 32x32 acc frag
typedef __attribute__((ext_vector_type(4)))  float f32x4_t;

__device__ __forceinline__ float sigf(float x) { return 1.0f / (1.0f + expf(-x)); }

__device__ __forceinline__ u16 f2bf(float x) {           // round-to-nearest-even
    unsigned u = __float_as_uint(x);
    u += 0x7fff + ((u >> 16) & 1);
    return (u16)(u >> 16);
}
__device__ __forceinline__ float bf2f(u16 h) {
    return __uint_as_float(((unsigned)h) << 16);
}

__device__ __forceinline__ void gload16(const u16* g, const u16* l) {
    __builtin_amdgcn_global_load_lds(
        (const __attribute__((address_space(1))) void*)g,
        (__attribute__((address_space(3))) void*)l, 16, 0, 0);
}

// ---------------------------------------------------------------- splitters
__global__ __launch_bounds__(256) void split_k(const float* __restrict__ src,
                                               u16* __restrict__ dH, u16* __restrict__ dL,
                                               int total4, int srcW4, int dstStride, int colOff) {
    int i = blockIdx.x * 256 + threadIdx.x;
    if (i >= total4) return;
    int row = i / srcW4;
    int c4 = (i - row * srcW4) << 2;
    float4 v = *(const float4*)(src + (size_t)row * ((size_t)srcW4 << 2) + c4);
    ushort4 H, L;
    H.x = f2bf(v.x); L.x = f2bf(v.x - bf2f(H.x));
    H.y = f2bf(v.y); L.y = f2bf(v.y - bf2f(H.y));
    H.z = f2bf(v.z); L.z = f2bf(v.z - bf2f(H.z));
    H.w = f2bf(v.w); L.w = f2bf(v.w - bf2f(H.w));
    size_t d = (size_t)row * dstStride + colOff + c4;
    *(ushort4*)(dH + d) = H;
    *(ushort4*)(dL + d) = L;
}

__global__ __launch_bounds__(256) void embed_split_k(const int* __restrict__ inp,
                                                     const float* __restrict__ etab,
                                                     u16* __restrict__ dH, u16* __restrict__ dL) {
    int i = blockIdx.x * 256 + threadIdx.x;
    int row = i >> 7;
    int c4 = (i & 127) << 2;
    float4 v = *(const float4*)(etab + (size_t)inp[row] * Hz + c4);
    ushort4 H, L;
    H.x = f2bf(v.x); L.x = f2bf(v.x - bf2f(H.x));
    H.y = f2bf(v.y); L.y = f2bf(v.y - bf2f(H.y));
    H.z = f2bf(v.z); L.z = f2bf(v.z - bf2f(H.z));
    H.w = f2bf(v.w); L.w = f2bf(v.w - bf2f(H.w));
    size_t d = (size_t)row * Hz + c4;
    *(ushort4*)(dH + d) = H;
    *(ushort4*)(dL + d) = L;
}

// per-batch transpose + split: enc[b][t][h] -> encT H/L [b][h][t]
__global__ __launch_bounds__(256) void tsplit_k(const float* __restrict__ enc,
                                                u16* __restrict__ dH, u16* __restrict__ dL) {
    __shared__ float ls[64][65];
    const int b = blockIdx.z;
    const int t0 = blockIdx.y * 64;
    const int h0 = blockIdx.x * 64;
    const int tid = threadIdx.x;
    const int rr = tid >> 4;
    const int cc = (tid & 15) << 2;
    const float* eb = enc + (size_t)b * Tz * Hz;
#pragma unroll
    for (int i = 0; i < 4; ++i) {
        int t = rr + i * 16;
        float4 v = *(const float4*)(eb + (size_t)(t0 + t) * Hz + h0 + cc);
        ls[t][cc] = v.x; ls[t][cc + 1] = v.y; ls[t][cc + 2] = v.z; ls[t][cc + 3] = v.w;
    }
    __syncthreads();
    u16* oH = dH + (size_t)b * Tz * Hz;
    u16* oL = dL + (size_t)b * Tz * Hz;
#pragma unroll
    for (int i = 0; i < 4; ++i) {
        int h = rr + i * 16;
        float x0 = ls[cc + 0][h], x1 = ls[cc + 1][h], x2 = ls[cc + 2][h], x3 = ls[cc + 3][h];
        ushort4 H, L;
        H.x = f2bf(x0); L.x = f2bf(x0 - bf2f(H.x));
        H.y = f2bf(x1); L.y = f2bf(x1 - bf2f(H.y));
        H.z = f2bf(x2); L.z = f2bf(x2 - bf2f(H.z));
        H.w = f2bf(x3); L.w = f2bf(x3 - bf2f(H.w));
        size_t d = (size_t)(h0 + h) * Tz + t0 + cc;
        *(ushort4*)(oH + d) = H;
        *(ushort4*)(oL + d) = L;
    }
}

// ------------------------------------------------------------------------------
// bf16x2-split MFMA GEMM (validated rounds 2-10):  C = act(A @ W^T + b1 + b2)
// ------------------------------------------------------------------------------
__device__ __forceinline__ void stage_tiles(const u16 (*L)[128][32],
    const u16* __restrict__ Ah, const u16* __restrict__ Al,
    const u16* __restrict__ Wh, const u16* __restrict__ Wl,
    int m0, int n0, int N, int K, int k0, int w, int l)
{
    const int srow = l >> 2, sslot = l & 3;
#pragma unroll
    for (int h = 0; h < 2; ++h) {
        const int rb = 32 * w + 16 * h;
        const int r = rb + srow;
        const int xr = (r >> 1) & 3;
        const int gk = k0 + ((sslot ^ xr) << 3);
        const size_t ao = (size_t)(m0 + r) * K + gk;
        int nrow = n0 + r; if (nrow >= N) nrow = N - 1;
        const size_t wo = (size_t)nrow * K + gk;
        gload16(Ah + ao, &L[0][rb][0]);
        gload16(Al + ao, &L[1][rb][0]);
        gload16(Wh + wo, &L[2][rb][0]);
        gload16(Wl + wo, &L[3][rb][0]);
    }
}

__global__ __launch_bounds__(256, 2) void gemm_mfma_split(
    const u16* __restrict__ Ah_, const u16* __restrict__ Al_,
    const u16* __restrict__ Wh_, const u16* __restrict__ Wl_,
    const float* __restrict__ b1, const float* __restrict__ b2,
    float* __restrict__ C, u16* __restrict__ CH, u16* __restrict__ CL,
    int M, int N, int K, int omode,
    long bsA, long bsW, int bsCrows, int cstride, int coff)
{
    __shared__ u16 lds[2][4][128][32];
    const int z = blockIdx.z;
    const u16* Ah = Ah_ + (size_t)z * bsA;
    const u16* Al = Al_ + (size_t)z * bsA;
    const u16* Wh = Wh_ + (size_t)z * bsW;
    const u16* Wl = Wl_ + (size_t)z * bsW;
    const int crow0 = z * bsCrows;
    const int tid = threadIdx.x;
    const int w = tid >> 6;
    const int l = tid & 63;
    const int m0 = blockIdx.y * 128;
    const int n0 = blockIdx.x * 128;
    const int wm = (w >> 1) * 64;
    const int wn = (w & 1) * 64;
    const int lr = l & 31;
    const int lk = l >> 5;

    f32x16_t acc[2][2];
#pragma unroll
    for (int si = 0; si < 2; ++si)
#pragma unroll
        for (int ni = 0; ni < 2; ++ni)
#pragma unroll
            for (int q = 0; q < 16; ++q) acc[si][ni][q] = 0.f;

    const int nk = K >> 5;
    stage_tiles(lds[0], Ah, Al, Wh, Wl, m0, n0, N, K, 0, w, l);
    __syncthreads();

    for (int t = 0; t < nk; ++t) {
        const int buf = t & 1;
        if (t + 1 < nk)
            stage_tiles(lds[buf ^ 1], Ah, Al, Wh, Wl, m0, n0, N, K, (t + 1) << 5, w, l);
        const u16 (*L)[128][32] = lds[buf];
#pragma unroll
        for (int kh = 0; kh < 2; ++kh) {
            const int k8 = lk + 2 * kh;
            bf16x8_t aH[2], aL[2], bH[2], bL[2];
#pragma unroll
            for (int si = 0; si < 2; ++si) {
                const int r = wm + si * 32 + lr;
                const int sl = (k8 ^ ((r >> 1) & 3)) << 3;
                aH[si] = *(const bf16x8_t*)&L[0][r][sl];
                aL[si] = *(const bf16x8_t*)&L[1][r][sl];
            }
#pragma unroll
            for (int ni = 0; ni < 2; ++ni) {
                const int r = wn + ni * 32 + lr;
                const int sl = (k8 ^ ((r >> 1) & 3)) << 3;
                bH[ni] = *(const bf16x8_t*)&L[2][r][sl];
                bL[ni] = *(const bf16x8_t*)&L[3][r][sl];
            }
#pragma unroll
            for (int si = 0; si < 2; ++si)
#pragma unroll
                for (int ni = 0; ni < 2; ++ni) {
                    acc[si][ni] = __builtin_amdgcn_mfma_f32_32x32x16_bf16(aH[si], bH[ni], acc[si][ni], 0, 0, 0);
                    acc[si][ni] = __builtin_amdgcn_mfma_f32_32x32x16_bf16(aH[si], bL[ni], acc[si][ni], 0, 0, 0);
                    acc[si][ni] = __builtin_amdgcn_mfma_f32_32x32x16_bf16(aL[si], bH[ni], acc[si][ni], 0, 0, 0);
                }
        }
        __syncthreads();
    }

    const int rbase = 4 * lk;
#pragma unroll
    for (int si = 0; si < 2; ++si)
#pragma unroll
        for (int ni = 0; ni < 2; ++ni) {
            const int n = n0 + wn + ni * 32 + lr;
            if (n >= N) continue;
            const float bias = (b1 ? b1[n] : 0.f) + (b2 ? b2[n] : 0.f);
#pragma unroll
            for (int q = 0; q < 16; ++q) {
                const int m = m0 + wm + si * 32 + (q & 3) + 8 * (q >> 2) + rbase;
                const int crow = crow0 + m;
                float x = acc[si][ni][q] + bias;
                if (omode == 0) {
                    C[(size_t)crow * N + n] = x;
                } else if (omode == 1) {
                    C[(size_t)crow * N + n] = tanhf(x);
                } else {
                    if (omode == 2) x = tanhf(x);
                    u16 h = f2bf(x);
                    CH[(size_t)crow * cstride + coff + n] = h;
                    CL[(size_t)crow * cstride + coff + n] = f2bf(x - bf2f(h));
                }
            }
        }
}

// ------------------------------------------------------------------------------
// Decoder GEMM (validated round 4): A = combH/L pre-split; W = etab fp32,
// split on the fly into swizzled LDS.
// ------------------------------------------------------------------------------
__global__ __launch_bounds__(256, 2) void gemm_dec(
    const u16* __restrict__ Ah, const u16* __restrict__ Al,
    const float* __restrict__ Wf, const float* __restrict__ b1,
    float* __restrict__ C, int M, int N, int K)
{
    __shared__ u16 lA[2][2][128][32];
    __shared__ u16 lB[2][2][128][32];
    const int tid = threadIdx.x;
    const int w = tid >> 6, l = tid & 63;
    const int m0 = blockIdx.y * 128, n0 = blockIdx.x * 128;
    const int wm = (w >> 1) * 64, wn = (w & 1) * 64;
    const int lr = l & 31, lk = l >> 5;
    const int srow = l >> 2, sslot = l & 3;

    f32x16_t acc[2][2];
#pragma unroll
    for (int si = 0; si < 2; ++si)
#pragma unroll
        for (int ni = 0; ni < 2; ++ni)
#pragma unroll
            for (int q = 0; q < 16; ++q) acc[si][ni][q] = 0.f;

    float4 br[4];

    auto loadB = [&](int k0) {
#pragma unroll
        for (int i = 0; i < 2; ++i) {
            const int c = tid * 2 + i;
            const int row = c >> 2, g = c & 3;
            int n = n0 + row; if (n >= N) n = N - 1;
            const float* s = Wf + (size_t)n * K + k0 + g * 8;
            br[2 * i]     = *(const float4*)s;
            br[2 * i + 1] = *(const float4*)(s + 4);
        }
    };
    auto writeB = [&](int buf) {
#pragma unroll
        for (int i = 0; i < 2; ++i) {
            const int c = tid * 2 + i;
            const int row = c >> 2, g = c & 3;
            const int gp = g ^ ((row >> 1) & 3);
            u16x8 H, L;
            const float* f = (const float*)&br[2 * i];
#pragma unroll
            for (int e = 0; e < 8; ++e) {
                u16 hh = f2bf(f[e]);
                H[e] = hh;
                L[e] = f2bf(f[e] - bf2f(hh));
            }
            *(u16x8*)&lB[buf][0][row][gp * 8] = H;
            *(u16x8*)&lB[buf][1][row][gp * 8] = L;
        }
    };
    auto stageA = [&](int buf, int k0) {
#pragma unroll
        for (int h = 0; h < 2; ++h) {
            const int rb = 32 * w + 16 * h;
            const int r = rb + srow;
            const int gk = k0 + ((sslot ^ ((r >> 1) & 3)) << 3);
            const size_t ao = (size_t)(m0 + r) * K + gk;
            gload16(Ah + ao, &lA[buf][0][rb][0]);
            gload16(Al + ao, &lA[buf][1][rb][0]);
        }
    };

    loadB(0);
    stageA(0, 0);
    writeB(0);
    __syncthreads();

    const int nk = K >> 5;
    for (int t = 0; t < nk; ++t) {
        const int buf = t & 1;
        if (t + 1 < nk) { loadB((t + 1) << 5); stageA(buf ^ 1, (t + 1) << 5); }
#pragma unroll
        for (int kh = 0; kh < 2; ++kh) {
            const int k8 = lk + 2 * kh;
            bf16x8_t aH[2], aL[2], bH[2], bL[2];
#pragma unroll
            for (int si = 0; si < 2; ++si) {
                const int r = wm + si * 32 + lr;
                const int sl = (k8 ^ ((r >> 1) & 3)) << 3;
                aH[si] = *(const bf16x8_t*)&lA[buf][0][r][sl];
                aL[si] = *(const bf16x8_t*)&lA[buf][1][r][sl];
            }
#pragma unroll
            for (int ni = 0; ni < 2; ++ni) {
                const int r = wn + ni * 32 + lr;
                const int sl = (k8 ^ ((r >> 1) & 3)) << 3;
                bH[ni] = *(const bf16x8_t*)&lB[buf][0][r][sl];
                bL[ni] = *(const bf16x8_t*)&lB[buf][1][r][sl];
            }
#pragma unroll
            for (int si = 0; si < 2; ++si)
#pragma unroll
                for (int ni = 0; ni < 2; ++ni) {
                    acc[si][ni] = __builtin_amdgcn_mfma_f32_32x32x16_bf16(aH[si], bH[ni], acc[si][ni], 0, 0, 0);
                    acc[si][ni] = __builtin_amdgcn_mfma_f32_32x32x16_bf16(aH[si], bL[ni], acc[si][ni], 0, 0, 0);
                    acc[si][ni] = __builtin_amdgcn_mfma_f32_32x32x16_bf16(aL[si], bH[ni], acc[si][ni], 0, 0, 0);
                }
        }
        if (t + 1 < nk) writeB(buf ^ 1);
        __syncthreads();
    }

    const int rbase = 4 * lk;
#pragma unroll
    for (int si = 0; si < 2; ++si)
#pragma unroll
        for (int ni = 0; ni < 2; ++ni) {
            const int n = n0 + wn + ni * 32 + lr;
            if (n >= N) continue;
            const float bias = b1 ? b1[n] : 0.f;
#pragma unroll
            for (int q = 0; q < 16; ++q) {
                const int m = m0 + wm + si * 32 + (q & 3) + 8 * (q >> 2) + rbase;
                C[(size_t)m * N + n] = acc[si][ni][q] + bias;
            }
        }
}

// ---------------------------------------------------- fp32 128x128 GEMM (Xp only)
__global__ __launch_bounds__(256, 2) void gemm128_wt(
    const float* __restrict__ A, const float* __restrict__ A2, int K1, int K,
    const float* __restrict__ W,
    const float* __restrict__ b1, const float* __restrict__ b2,
    float* __restrict__ C, int M, int N, int act) {
    __shared__ float As[16][132];
    __shared__ float Ws[16][132];
    const int tid = threadIdx.x;
    const int m0 = blockIdx.y * 128;
    const int n0 = blockIdx.x * 128;
    const int lr = tid >> 2;
    const int lc = (tid & 3) << 2;
    const int ty = tid >> 4;
    const int tx = tid & 15;
    float acc[2][2][4][4] = {{{{0.f}}}};
    for (int kc = 0; kc < K; kc += 16) {
        const int k = kc + lc;
#pragma unroll
        for (int h = 0; h < 2; ++h) {
            const int r = lr + 64 * h;
            float4 av;
            if (k < K1) av = *(const float4*)(A + (size_t)(m0 + r) * K1 + k);
            else        av = *(const float4*)(A2 + (size_t)(m0 + r) * (K - K1) + (k - K1));
            As[lc + 0][r] = av.x; As[lc + 1][r] = av.y;
            As[lc + 2][r] = av.z; As[lc + 3][r] = av.w;
            const int n = n0 + r;
            float4 wv = make_float4(0.f, 0.f, 0.f, 0.f);
            if (n < N) wv = *(const float4*)(W + (size_t)n * K + k);
            Ws[lc + 0][r] = wv.x; Ws[lc + 1][r] = wv.y;
            Ws[lc + 2][r] = wv.z; Ws[lc + 3][r] = wv.w;
        }
        __syncthreads();
#pragma unroll
        for (int kt = 0; kt < 16; ++kt) {
            float a[2][4], b[2][4];
            *(float4*)a[0] = *(const float4*)&As[kt][ty << 2];
            *(float4*)a[1] = *(const float4*)&As[kt][64 + (ty << 2)];
            *(float4*)b[0] = *(const float4*)&Ws[kt][tx << 2];
            *(float4*)b[1] = *(const float4*)&Ws[kt][64 + (tx << 2)];
#pragma unroll
            for (int rg = 0; rg < 2; ++rg)
#pragma unroll
                for (int cg = 0; cg < 2; ++cg)
#pragma unroll
                    for (int i = 0; i < 4; ++i)
#pragma unroll
                        for (int j = 0; j < 4; ++j)
                            acc[rg][cg][i][j] = fmaf(a[rg][i], b[cg][j], acc[rg][cg][i][j]);
        }
        __syncthreads();
    }
#pragma unroll
    for (int rg = 0; rg < 2; ++rg)
#pragma unroll
    for (int i = 0; i < 4; ++i) {
        const int m = m0 + rg * 64 + (ty << 2) + i;
#pragma unroll
        for (int cg = 0; cg < 2; ++cg) {
            const int nbase = n0 + cg * 64 + (tx << 2);
            float4 v;
            float* vp = (float*)&v;
#pragma unroll
            for (int j = 0; j < 4; ++j) {
                int n = nbase + j;
                float x = acc[rg][cg][i][j];
                if (n < N) {
                    if (b1) x += b1[n];
                    if (b2) x += b2[n];
                    if (act == 1) x = tanhf(x);
                }
                vp[j] = x;
            }
            if (nbase + 3 < N) {
                *(float4*)(C + (size_t)m * N + nbase) = v;
            } else {
                for (int j = 0; j < 4; ++j)
                    if (nbase + j < N) C[(size_t)m * N + nbase + j] = vp[j];
            }
        }
    }
}

// ------------------------------------------------ poison enc for data-polling
__global__ __launch_bounds__(256) void poison_k(float* __restrict__ enc) {
    int i = blockIdx.x * 256 + threadIdx.x;      // over 8,388,608 / 4
    uint4 p = make_uint4(POISON, POISON, POISON, POISON);
    *(uint4*)(enc + (size_t)i * 4) = *(uint4*)&p;
}

// ------------------------------------------------------------------------------
// Persistent encoder LSTM v7: round-10 structure (128 blocks = 4 batch-groups
// x 32 j-slices, poison polling with ONE asm-batched MLP poll per round) PLUS:
//  (a) the block's 64 Whh gate-rows staged into LDS ONCE (128 KB) — the dot no
//      longer exposes per-step L2 latency (was ~2-3us/step hidden stall);
//  (b) per-gate accumulators split even/odd to halve the dependent-fma chain.
// LDS total ~146 KB -> still 1 block/CU, 4 waves (occupancy unchanged).
// ------------------------------------------------------------------------------
__global__ __launch_bounds__(256) void enc_persist_k(
    const float* __restrict__ Xg, const float* __restrict__ Whh,
    float* __restrict__ enc)
{
    __shared__ float wlds[64][516];    // 64 gate-rows x 512 (+4 pad) = 129 KB
    __shared__ float hlds[8][516];     // 8 batches x 512 (+4 pad)
    __shared__ float ex[128][2];       // upper gate-pair exchange
    const int tid = threadIdx.x;
    const int g = blockIdx.x >> 5;     // batch group (8 batches)
    const int sidx = blockIdx.x & 31;  // j-slice
    const int j0 = sidx * 16;
    const int bb = tid & 7;
    const int q = tid >> 3;            // 0..31
    const int jj = q & 15;
    const int gp = q >> 4;             // 0: gates i,f   1: gates g,o

    // stage the 64 Whh rows (row r = gate*16 + j2 -> Whh[gate*512 + j0 + j2])
    for (int i = tid; i < 64 * 128; i += 256) {
        const int r = i >> 7;                    // 0..63
        const int c4 = (i & 127) << 2;           // 0..508
        const int gate = r >> 4, j2 = r & 15;
        *(float4*)&wlds[r][c4] =
            *(const float4*)(Whh + (size_t)(gate * 512 + j0 + j2) * Hz + c4);
    }
    const float* w0 = &wlds[(2 * gp) * 16 + jj][0];
    const float* w1 = &wlds[(2 * gp + 1) * 16 + jj][0];

    // poll mapping: wave w, lane l -> rows hb0=2w, hb1=2w+1, col base l*4
    const int wv = tid >> 6, ln = tid & 63;
    const int hb0 = 2 * wv, hb1 = 2 * wv + 1;
    const int cb = ln * 4;                       // 0..252
    const bool need0 = (cb >> 4) != sidx;        // chunks at col cb
    const bool need1 = ((cb >> 4) + 16) != sidx; // chunks at col cb+256
    u64 a0 = (u64)(size_t)(enc + ((size_t)(g * 8 + hb0) * Tz + 0) * Hz + cb);
    u64 a1 = (u64)(size_t)(enc + ((size_t)(g * 8 + hb1) * Tz + 0) * Hz + cb);
    float c_reg = 0.f;                 // tid<128: cell state for (g*8+bb, j0+jj)
    __syncthreads();

    for (int t = 0; t < Tz; ++t) {
        // xg gather (independent of h; overlaps the poll)
        float xv0 = 0.f, xv1 = 0.f, xv2 = 0.f, xv3 = 0.f;
        if (tid < 128) {
            const float* xp = Xg + ((size_t)(g * 8 + bb) * Tz + t) * 2048 + j0 + jj;
            xv0 = xp[0]; xv1 = xp[512]; xv2 = xp[1024]; xv3 = xp[1536];
        }

        float acc0 = 0.f, acc1 = 0.f;
        if (t > 0) {
            f32x4_t v0, v1, v2, v3;
            for (;;) {
                asm volatile(
                    "global_load_dwordx4 %0, %4, off sc0 sc1\n\t"
                    "global_load_dwordx4 %1, %4, off offset:1024 sc0 sc1\n\t"
                    "global_load_dwordx4 %2, %5, off sc0 sc1\n\t"
                    "global_load_dwordx4 %3, %5, off offset:1024 sc0 sc1\n\t"
                    "s_waitcnt vmcnt(0)"
                    : "=&v"(v0), "=&v"(v1), "=&v"(v2), "=&v"(v3)
                    : "v"(a0), "v"(a1)
                    : "memory");
                bool bad = false;
                if (need0) {
                    bad |= (__float_as_uint(v0.x) == POISON) | (__float_as_uint(v0.y) == POISON) |
                           (__float_as_uint(v0.z) == POISON) | (__float_as_uint(v0.w) == POISON) |
                           (__float_as_uint(v2.x) == POISON) | (__float_as_uint(v2.y) == POISON) |
                           (__float_as_uint(v2.z) == POISON) | (__float_as_uint(v2.w) == POISON);
                }
                if (need1) {
                    bad |= (__float_as_uint(v1.x) == POISON) | (__float_as_uint(v1.y) == POISON) |
                           (__float_as_uint(v1.z) == POISON) | (__float_as_uint(v1.w) == POISON) |
                           (__float_as_uint(v3.x) == POISON) | (__float_as_uint(v3.y) == POISON) |
                           (__float_as_uint(v3.z) == POISON) | (__float_as_uint(v3.w) == POISON);
                }
                if (!bad) break;
                __builtin_amdgcn_s_sleep(1);
            }
            if (need0) {
                *(f32x4_t*)&hlds[hb0][cb] = v0;
                *(f32x4_t*)&hlds[hb1][cb] = v2;
            }
            if (need1) {
                *(f32x4_t*)&hlds[hb0][cb + 256] = v1;
                *(f32x4_t*)&hlds[hb1][cb + 256] = v3;
            }
            a0 += 2048; a1 += 2048;              // advance to next t-1
            __syncthreads();
            // dot: 2 gate rows x 512 k, w from LDS, 2-way split chains
            float a0e = 0.f, a0o = 0.f, a1e = 0.f, a1o = 0.f;
#pragma unroll 8
            for (int k = 0; k < Hz; k += 8) {
                float4 wa0 = *(const float4*)(w0 + k);
                float4 wb0 = *(const float4*)(w0 + k + 4);
                float4 wa1 = *(const float4*)(w1 + k);
                float4 wb1 = *(const float4*)(w1 + k + 4);
                float4 ha = *(const float4*)&hlds[bb][k];
                float4 hb_ = *(const float4*)&hlds[bb][k + 4];
                a0e = fmaf(wa0.x, ha.x, a0e);  a0e = fmaf(wa0.y, ha.y, a0e);
                a0e = fmaf(wa0.z, ha.z, a0e);  a0e = fmaf(wa0.w, ha.w, a0e);
                a0o = fmaf(wb0.x, hb_.x, a0o); a0o = fmaf(wb0.y, hb_.y, a0o);
                a0o = fmaf(wb0.z, hb_.z, a0o); a0o = fmaf(wb0.w, hb_.w, a0o);
                a1e = fmaf(wa1.x, ha.x, a1e);  a1e = fmaf(wa1.y, ha.y, a1e);
                a1e = fmaf(wa1.z, ha.z, a1e);  a1e = fmaf(wa1.w, ha.w, a1e);
                a1o = fmaf(wb1.x, hb_.x, a1o); a1o = fmaf(wb1.y, hb_.y, a1o);
                a1o = fmaf(wb1.z, hb_.z, a1o); a1o = fmaf(wb1.w, hb_.w, a1o);
            }
            acc0 = a0e + a0o;
            acc1 = a1e + a1o;
        }
        // exchange upper gate pair, finalize
        if (tid >= 128) { ex[tid - 128][0] = acc0; ex[tid - 128][1] = acc1; }
        __syncthreads();
        if (tid < 128) {
            float gi = acc0 + xv0;
            float gf = acc1 + xv1;
            float gg = ex[tid][0] + xv2;
            float go = ex[tid][1] + xv3;
            float ig = sigf(gi), fg = sigf(gf), G = tanhf(gg), og = sigf(go);
            c_reg = fg * c_reg + ig * G;
            float hn = og * tanhf(c_reg);
            hlds[bb][j0 + jj] = hn;                       // own-slice shortcut
            __hip_atomic_store(enc + ((size_t)(g * 8 + bb) * Tz + t) * Hz + j0 + jj, hn,
                               __ATOMIC_RELAXED, __HIP_MEMORY_SCOPE_AGENT);
        }
        // no trailing barrier: next poll writes only non-own hlds cells;
        // its post-poll barrier orders finalize's hlds writes before the dot.
    }
}

// ---------------------------- positional LSTM + mu_w/sig + mu scan (single block)
__global__ __launch_bounds__(640) void pos_k(const float* __restrict__ Xp,
                                             const float* __restrict__ Wphh,
                                             const float* __restrict__ Wmu,
                                             const float* __restrict__ bmu,
                                             const float* __restrict__ Wsig,
                                             const float* __restrict__ bsig,
                                             float* __restrict__ muv,
                                             float* __restrict__ sgv) {
    __shared__ float hs[Bz][Pz];
    __shared__ float ws[80][Pz];
    __shared__ float mw[Bz][4];
    __shared__ float muprev[Bz];
    __shared__ float wmu_s[4][Pz];
    const int tid = threadIdx.x;
    for (int i = tid; i < 80 * Pz; i += 640) ws[i / Pz][i % Pz] = Wphh[i];
    for (int i = tid; i < 3 * Pz; i += 640) wmu_s[i / Pz][i % Pz] = Wmu[i];
    if (tid < Pz) wmu_s[3][tid] = Wsig[tid];
    if (tid < Bz) muprev[tid] = 0.f;
    const int b = tid / Pz;
    const int p = tid % Pz;
    float c_r = 0.f;
    hs[b][p] = 0.f;
    __syncthreads();
    for (int t = 0; t < Tz; ++t) {
        const float* xp = Xp + ((size_t)b * Tz + t) * 80;
        float a0 = xp[p], a1 = xp[20 + p], a2 = xp[40 + p], a3 = xp[60 + p];
#pragma unroll
        for (int k = 0; k < Pz; ++k) {
            float hk = hs[b][k];
            a0 += ws[p][k] * hk;
            a1 += ws[20 + p][k] * hk;
            a2 += ws[40 + p][k] * hk;
            a3 += ws[60 + p][k] * hk;
        }
        float ig = sigf(a0), fg = sigf(a1), gg = tanhf(a2), og = sigf(a3);
        c_r = fg * c_r + ig * gg;
        float hn = og * tanhf(c_r);
        __syncthreads();
        hs[b][p] = hn;
        __syncthreads();
        if (tid < 128) {
            int bb = tid >> 2, o = tid & 3;
            float s = (o < 3) ? bmu[o] : bsig[0];
#pragma unroll
            for (int k = 0; k < Pz; ++k) s += wmu_s[o][k] * hs[bb][k];
            mw[bb][o] = s;
        }
        __syncthreads();
        if (tid < Bz) {
            float w0 = fmaxf(mw[tid][0], 0.f);
            float w1 = fmaxf(mw[tid][1], 0.f);
            float w2 = fmaxf(mw[tid][2], 0.f);
            float m = w0 * muprev[tid] + w1 * (1.f / 512.f) + w2 * (t + 1.f) / 512.f;
            muprev[tid] = m;
            muv[tid * Tz + t] = m;
            sgv[tid * Tz + t] = sigf(mw[tid][3]);
        }
        __syncthreads();
    }
}

// ---------------------- attention weights, L2-normalized rows, split bf16 output
__global__ __launch_bounds__(256) void attw_k(const float* __restrict__ muv,
                                              const float* __restrict__ sgv,
                                              u16* __restrict__ wH,
                                              u16* __restrict__ wL) {
    const int row = blockIdx.x * 4 + (threadIdx.x >> 6);
    const int lane = threadIdx.x & 63;
    const int b = row >> 9, j = row & 511;
    const float m = muv[b * Tz + j];
    const float s = sgv[b * Tz + j];
    const float inv = 0.5f / (s * s);
    const float rj = 1.0f / (j + 1.0f);
    float vals[8];
    float ss = 0.f;
#pragma unroll
    for (int i = 0; i < 8; ++i) {
        int t = lane + i * 64;
        float v = 0.f;
        if (t <= j) {
            float d = t * rj - m;
            v = expf(-d * d * inv);
        }
        vals[i] = v;
        ss += v * v;
    }
    for (int off = 32; off; off >>= 1) ss += __shfl_xor(ss, off);
    float nrm = 1.0f / fmaxf(sqrtf(ss), 1e-12f);
    u16* rH = wH + (size_t)row * Tz;
    u16* rL = wL + (size_t)row * Tz;
#pragma unroll
    for (int i = 0; i < 8; ++i) {
        float v = vals[i] * nrm;
        u16 h = f2bf(v);
        rH[lane + i * 64] = h;
        rL[lane + i * 64] = f2bf(v - bf2f(h));
    }
}

// ---------------------------------------------------------------------------------
extern "C" void kernel_launch(void* const* d_in, const int* in_sizes, int n_in,
                              void* d_out, int out_size, void* d_ws, size_t ws_size,
                              hipStream_t stream) {
    const int*   inp      = (const int*)d_in[0];
    const float* etab     = (const float*)d_in[3];
    const float* dec_bias = (const float*)d_in[4];
    const float* W_ih     = (const float*)d_in[5];
    const float* W_hh     = (const float*)d_in[6];
    const float* b_ih     = (const float*)d_in[7];
    const float* b_hh     = (const float*)d_in[8];
    const float* Wp_ih    = (const float*)d_in[9];
    const float* Wp_hh    = (const float*)d_in[10];
    const float* bp_ih    = (const float*)d_in[11];
    const float* bp_hh    = (const float*)d_in[12];
    const float* W_mu     = (const float*)d_in[13];
    const float* b_mu     = (const float*)d_in[14];
    const float* W_sig    = (const float*)d_in[15];
    const float* b_sig    = (const float*)d_in[16];
    const float* W_cat    = (const float*)d_in[17];
    const float* b_cat    = (const float*)d_in[18];

    float* out = (float*)d_out;
    // All transients inside d_out (163.84M floats); dead before decoder rewrite.
    float*    Xg    = out;                          // 33,554,432 f
    float*    enc   = out + 33554432;               //  8,388,608
    float*    Xp    = out + 41959424;               //  1,310,720
    float*    muv   = out + 43270144;               //     16,384
    float*    sgv   = out + 43286528;               //     16,384
    u16*  embH   = (u16*)(out + 43302912);          // 16384x512
    u16*  embL   = (u16*)(out + 47497216);
    u16*  WihH   = (u16*)(out + 51691520);          // 2048x512
    u16*  WihL   = (u16*)(out + 52215808);
    u16*  WcatH  = (u16*)(out + 52740096);          // 512x1024
    u16*  WcatL  = (u16*)(out + 53002240);
    u16*  catH   = (u16*)(out + 53264384);          // 16384x1024
    u16*  catL   = (u16*)(out + 61652992);
    u16*  attwH  = (u16*)(out + 70041600);          // 32x512x512
    u16*  attwL  = (u16*)(out + 74235904);
    u16*  encTH  = (u16*)(out + 78430208);          // 32x512x512
    u16*  encTL  = (u16*)(out + 82624512);          // end 86,818,816 < 163,840,000

    u16* combH = (u16*)d_ws;                        // 16384x512 u16
    u16* combL = (u16*)((char*)d_ws + 16777216);    // 33,554,432 B total (proven)

    // 1. poison enc (readiness sentinel) + input splits
    poison_k<<<8192, 256, 0, stream>>>(enc);
    embed_split_k<<<8192, 256, 0, stream>>>(inp, etab, embH, embL);
    split_k<<<1024, 256, 0, stream>>>(W_ih, WihH, WihL, 2048 * 128, 128, 512, 0);
    split_k<<<512, 256, 0, stream>>>(W_cat, WcatH, WcatL, 512 * 256, 256, 1024, 0);

    // 2. Xg = emb @ W_ih^T + b_ih + b_hh  (MFMA split, fp32 out)
    gemm_mfma_split<<<dim3(16, 128), 256, 0, stream>>>(
        embH, embL, WihH, WihL, b_ih, b_hh, Xg, nullptr, nullptr,
        16384, 2048, 512, 0, 0, 0, 0, 0, 0);

    // 3. encoder recurrence — persistent, poison polling, LDS-resident Whh
    enc_persist_k<<<128, 256, 0, stream>>>(Xg, W_hh, enc);

    // 4. enc -> cat cols [512,1024); enc -> encT H/L
    split_k<<<8192, 256, 0, stream>>>(enc, catH, catL, 16384 * 128, 128, 1024, 512);
    tsplit_k<<<dim3(8, 8, 32), 256, 0, stream>>>(enc, encTH, encTL);

    // 5. Xp = enc @ Wp_ih^T + biases (fp32, N=80)
    gemm128_wt<<<dim3(1, 128), 256, 0, stream>>>(enc, nullptr, 512, 512, Wp_ih, bp_ih, bp_hh,
                                                 Xp, 16384, 80, 0);
    // 6. positional LSTM + heads + mu scan
    pos_k<<<1, 640, 0, stream>>>(Xp, Wp_hh, W_mu, b_mu, W_sig, b_sig, muv, sgv);
    // 7. attention weights -> bf16 split
    attw_k<<<4096, 256, 0, stream>>>(muv, sgv, attwH, attwL);

    // 8. ctx = attw @ encT^T (batched MFMA) -> cat cols [0,512) split bf16
    gemm_mfma_split<<<dim3(4, 4, 32), 256, 0, stream>>>(
        attwH, attwL, encTH, encTL, nullptr, nullptr, nullptr, catH, catL,
        512, 512, 512, 3, (long)512 * 512, (long)512 * 512, 512, 1024, 0);

    // 9. comb = tanh(cat @ W_cat^T + b_cat) -> split bf16 into ws
    gemm_mfma_split<<<dim3(4, 128), 256, 0, stream>>>(
        catH, catL, WcatH, WcatL, b_cat, nullptr, nullptr, combH, combL,
        16384, 512, 1024, 2, 0, 0, 0, 512, 0);

    // 10. decoded = comb @ embedding^T + dec_bias
    gemm_dec<<<dim3(79, 128), 256, 0, stream>>>(
        combH, combL, etab, dec_bias, out, 16384, 10000, 512);
}